// Round 13
// baseline (511.626 us; speedup 1.0000x reference)
//
#include <hip/hip_runtime.h>

typedef unsigned long long ull;

#define HIDDEN 32
#define SORTK 30
#define KCAP 256              // max nodes/graph fast path (mean 122, sd 11; 12 sigma)
#define GPB 4                 // graphs per block (1 wave per graph)
#define BSH 7                 // 128 nodes per bucket
#define BNODES (1 << BSH)
#define BCAP 1536
#define HMAX 2048
#define NSEG 256
#define EID_BITS 22           // E = 2.5M < 4.19M
#define EID_MASK ((1u << EID_BITS) - 1)

static inline int ceil_div_i(long long a, int b){ return (int)((a + b - 1) / b); }

// ---------------- phase 1: per-segment LDS histogram ----------------
__global__ __launch_bounds__(1024) void hist_kernel(const int* __restrict__ dsts,
                                                    int* __restrict__ hist,
                                                    int E, int NB, int segsz){
  __shared__ int h[HMAX];
  for (int i = threadIdx.x; i < NB; i += 1024) h[i] = 0;
  __syncthreads();
  int seg = blockIdx.x;
  int e0 = seg * segsz;
  int e1 = e0 + segsz; if (e1 > E) e1 = E;
  for (int e = e0 + threadIdx.x; e < e1; e += 1024)
    atomicAdd(&h[dsts[e] >> BSH], 1);
  __syncthreads();
  for (int i = threadIdx.x; i < NB; i += 1024) hist[seg * NB + i] = h[i];
}

// ---------------- phase 2a: per-bucket prefix over segments (1 wave / bucket) -------
__global__ __launch_bounds__(256) void segscanA(const int* __restrict__ hist,
                                                int* __restrict__ segoff,
                                                int* __restrict__ btot,
                                                int NB, int S){
  int wv = (blockIdx.x * 256 + threadIdx.x) >> 6;
  int lane = threadIdx.x & 63;
  if (wv >= NB) return;
  int b = wv;
  int run_base = 0;
  for (int chunk = 0; chunk < S; chunk += 64){
    int s = chunk + lane;
    int v = (s < S) ? hist[(size_t)s * NB + b] : 0;
    int x = v;
    #pragma unroll
    for (int o = 1; o < 64; o <<= 1){ int y = __shfl_up(x, o, 64); if (lane >= o) x += y; }
    if (s < S) segoff[(size_t)s * NB + b] = run_base + x - v;
    run_base += __shfl(x, 63, 64);
  }
  if (lane == 0) btot[b] = run_base;
}

// ---------------- phase 2b: exclusive scan of bucket totals (1 block) ----------------
__global__ __launch_bounds__(1024) void segscanB(const int* __restrict__ btot,
                                                 int* __restrict__ bbase, int NB){
  int t = threadIdx.x;
  int b0 = t * 2, b1 = t * 2 + 1;
  int v0 = (b0 < NB) ? btot[b0] : 0;
  int v1 = (b1 < NB) ? btot[b1] : 0;
  int pair = v0 + v1;
  int lane = t & 63, wid = t >> 6;
  int x = pair;
  for (int o = 1; o < 64; o <<= 1){ int y = __shfl_up(x, o, 64); if (lane >= o) x += y; }
  __shared__ int wsum[16]; __shared__ int woff[16];
  if (lane == 63) wsum[wid] = x;
  __syncthreads();
  if (t == 0){ int run = 0; for (int w = 0; w < 16; w++){ woff[w] = run; run += wsum[w]; } }
  __syncthreads();
  int excl = x - pair + woff[wid];
  if (b0 < NB) bbase[b0] = excl;
  if (b1 < NB) bbase[b1] = excl + v0;
}

// ---------------- phase 3: scatter 32-bit key (ld,eid), block-private regions ------
__global__ __launch_bounds__(1024) void scatter_kernel(const int* __restrict__ dsts,
                                                       const int* __restrict__ segoff,
                                                       const int* __restrict__ bbase,
                                                       unsigned* __restrict__ staging,
                                                       int E, int NB, int segsz){
  __shared__ int cur[HMAX];
  int seg = blockIdx.x;
  for (int i = threadIdx.x; i < NB; i += 1024) cur[i] = segoff[(size_t)seg * NB + i] + bbase[i];
  __syncthreads();
  int e0 = seg * segsz;
  int e1 = e0 + segsz; if (e1 > E) e1 = E;
  for (int e = e0 + threadIdx.x; e < e1; e += 1024){
    int d = dsts[e];
    int slot = atomicAdd(&cur[d >> BSH], 1);
    staging[slot] = ((unsigned)(d & (BNODES - 1)) << EID_BITS) | (unsigned)e;
  }
}

// ---------------- phase 4: per-bucket LDS bin + parallel rank -> CSR ----------------
// 256 threads; edge loops stride 256, node sections guard t<128. All cross-wave
// LDS dependencies synchronized with UNIFORM __syncthreads().
__global__ __launch_bounds__(256) void bucket_sort_kernel(
    const int* __restrict__ bbase, const unsigned* __restrict__ staging,
    const int* __restrict__ srcs,
    int* __restrict__ csr, int* __restrict__ offs,
    float* __restrict__ dis, int N, int NB, int E){
  __shared__ unsigned ebuf[BCAP];
  __shared__ unsigned obuf[BCAP];
  __shared__ int cnt[BNODES];
  __shared__ int cur[BNODES];
  __shared__ int base0[BNODES];
  __shared__ int w0tot;
  int b = blockIdx.x, t = threadIdx.x;
  int n0 = b << BSH;
  int n1 = n0 + BNODES; if (n1 > N) n1 = N;
  int gbeg = bbase[b];
  int gend = (b + 1 < NB) ? bbase[b + 1] : E;
  int cnt_all = gend - gbeg;
  if (t < BNODES) cnt[t] = 0;
  __syncthreads();

  if (cnt_all <= BCAP){
    for (int i = t; i < cnt_all; i += 256){
      unsigned k = staging[gbeg + i];
      ebuf[i] = k;
      atomicAdd(&cnt[k >> EID_BITS], 1);
    }
    __syncthreads();
    int v = 0, x = 0;
    if (t < BNODES){
      v = cnt[t];
      int lane = t & 63, wid = t >> 6;
      x = v;
      for (int o = 1; o < 64; o <<= 1){ int y = __shfl_up(x, o, 64); if (lane >= o) x += y; }
      if (wid == 0 && lane == 63) w0tot = x;
    }
    __syncthreads();   // uniform: makes w0tot visible to wave 1
    if (t < BNODES){
      int wid = t >> 6;
      int ls = x - v + (wid ? w0tot : 0);
      cur[t] = ls;
      base0[t] = ls;
      int n = n0 + t;
      if (n < n1){
        float dd = (float)v + 1.0f;
        dis[n]  = __fdiv_rn(1.0f, __fsqrt_rn(dd));
        offs[n] = gbeg + ls;
      }
    }
    __syncthreads();
    for (int i = t; i < cnt_all; i += 256){
      unsigned k = ebuf[i];
      int pos = atomicAdd(&cur[k >> EID_BITS], 1);
      obuf[pos] = k;
    }
    __syncthreads();
    for (int i = t; i < cnt_all; i += 256){
      unsigned k = obuf[i];
      int nd = (int)(k >> EID_BITS);
      int base = base0[nd];
      int vn = cnt[nd];
      int r = 0;
      for (int j = 0; j < vn; j++) r += (obuf[base + j] < k) ? 1 : 0;
      csr[gbeg + base + r] = srcs[k & EID_MASK];
    }
  } else {
    // statistically unreachable fallback (correct, slow)
    if (t < BNODES){
      int n = n0 + t;
      int deg = 0;
      if (n < n1){
        for (int i = gbeg; i < gend; i++) if ((int)(staging[i] >> EID_BITS) == t) deg++;
        float dd = (float)deg + 1.0f;
        dis[n] = __fdiv_rn(1.0f, __fsqrt_rn(dd));
      }
      cnt[t] = (n < n1) ? deg : 0;
    }
    __syncthreads();
    if (t < BNODES){
      int n = n0 + t;
      if (n < n1){
        int deg = cnt[t];
        int ls = gbeg; for (int q = 0; q < t; q++) ls += cnt[q];
        offs[n] = ls;
        unsigned prev = 0;
        for (int o = 0; o < deg; o++){
          unsigned best = 0xFFFFFFFFu;
          for (int i = gbeg; i < gend; i++){
            unsigned k = staging[i];
            if ((int)(k >> EID_BITS) == t && (o == 0 || k > prev) && k < best) best = k;
          }
          csr[ls + o] = srcs[best & EID_MASK]; prev = best;
        }
      }
    }
  }
  if (b == 0 && t == 0) offs[N] = E;
}

// ---------------- per-node matmul h = x @ W ----------------
template<int K>
__global__ void node_matmul(const float* __restrict__ xin, const float* __restrict__ W,
                            float* __restrict__ H, int N){
  __shared__ float Ws[K * 32];
  for (int i = threadIdx.x; i < K * 32; i += blockDim.x) Ws[i] = W[i];
  __syncthreads();
  int tid = blockIdx.x * blockDim.x + threadIdx.x;
  int n = tid >> 5, c = tid & 31;
  if (n >= N) return;
  const float* xr = xin + (size_t)n * K;
  float acc = 0.f;
  #pragma unroll
  for (int k = 0; k < K; k++) acc = fmaf(xr[k], Ws[k * 32 + c], acc);
  H[(size_t)n * 32 + c] = acc;
}

// ---------------- GCN aggregation helpers ----------------
__device__ __forceinline__ float4 acc_edge(float4 a, float4 h, float w){
  a.x = __fadd_rn(a.x, __fmul_rn(h.x, w));
  a.y = __fadd_rn(a.y, __fmul_rn(h.y, w));
  a.z = __fadd_rn(a.z, __fmul_rn(h.z, w));
  a.w = __fadd_rn(a.w, __fmul_rn(h.w, w));
  return a;
}

// core agg body: returns v = relu(agg + selfterm + bias) for this lane's quad
__device__ __forceinline__ float4 agg_body(const float* __restrict__ H,
                                           const int* __restrict__ offsets,
                                           const int* __restrict__ csr,
                                           const float* __restrict__ dis,
                                           const float* __restrict__ bias,
                                           int n, int qw){
  const float4* __restrict__ H4 = (const float4*)H;
  float dn = dis[n];
  int s = offsets[n], e = offsets[n + 1];
  float4 acc = make_float4(0.f, 0.f, 0.f, 0.f);
  int i = s;
  for (; i + 8 <= e; i += 8){
    int s0 = csr[i],   s1 = csr[i+1], s2 = csr[i+2], s3 = csr[i+3];
    int s4 = csr[i+4], s5 = csr[i+5], s6 = csr[i+6], s7 = csr[i+7];
    float4 h0 = H4[(size_t)s0 * 8 + qw];
    float4 h1 = H4[(size_t)s1 * 8 + qw];
    float4 h2 = H4[(size_t)s2 * 8 + qw];
    float4 h3 = H4[(size_t)s3 * 8 + qw];
    float4 h4 = H4[(size_t)s4 * 8 + qw];
    float4 h5 = H4[(size_t)s5 * 8 + qw];
    float4 h6 = H4[(size_t)s6 * 8 + qw];
    float4 h7 = H4[(size_t)s7 * 8 + qw];
    float w0 = __fmul_rn(dis[s0], dn), w1 = __fmul_rn(dis[s1], dn);
    float w2 = __fmul_rn(dis[s2], dn), w3 = __fmul_rn(dis[s3], dn);
    float w4 = __fmul_rn(dis[s4], dn), w5 = __fmul_rn(dis[s5], dn);
    float w6 = __fmul_rn(dis[s6], dn), w7 = __fmul_rn(dis[s7], dn);
    acc = acc_edge(acc, h0, w0);
    acc = acc_edge(acc, h1, w1);
    acc = acc_edge(acc, h2, w2);
    acc = acc_edge(acc, h3, w3);
    acc = acc_edge(acc, h4, w4);
    acc = acc_edge(acc, h5, w5);
    acc = acc_edge(acc, h6, w6);
    acc = acc_edge(acc, h7, w7);
  }
  for (; i < e; i++){
    int sr = csr[i];
    float w = __fmul_rn(dis[sr], dn);
    acc = acc_edge(acc, H4[(size_t)sr * 8 + qw], w);
  }
  float4 hn = H4[(size_t)n * 8 + qw];
  float sw = __fmul_rn(dn, dn);
  float4 bb = ((const float4*)bias)[qw];
  float4 v;
  v.x = fmaxf(__fadd_rn(__fadd_rn(acc.x, __fmul_rn(hn.x, sw)), bb.x), 0.f);
  v.y = fmaxf(__fadd_rn(__fadd_rn(acc.y, __fmul_rn(hn.y, sw)), bb.y), 0.f);
  v.z = fmaxf(__fadd_rn(__fadd_rn(acc.z, __fmul_rn(hn.z, sw)), bb.z), 0.f);
  v.w = fmaxf(__fadd_rn(__fadd_rn(acc.w, __fmul_rn(hn.w, sw)), bb.w), 0.f);
  return v;
}

// final-layer agg: writes A (+ sort key)
__global__ __launch_bounds__(256) void agg_kernel(const float* __restrict__ H,
                           const int* __restrict__ offsets,
                           const int* __restrict__ csr, const float* __restrict__ dis,
                           const float* __restrict__ bias, float* __restrict__ A,
                           float* __restrict__ keyout, int N){
  int tid = blockIdx.x * 256 + threadIdx.x;
  int n = tid >> 3, qw = tid & 7;
  if (n >= N) return;
  float4 v = agg_body(H, offsets, csr, dis, bias, n, qw);
  ((float4*)A)[(size_t)n * 8 + qw] = v;
  if (keyout != nullptr && qw == 7) keyout[n] = v.w;
}

// fused agg + next-layer matmul (bit-identical to node_matmul<32>, k ascending)
__global__ __launch_bounds__(256) void agg_mm_kernel(const float* __restrict__ H,
                           const int* __restrict__ offsets,
                           const int* __restrict__ csr, const float* __restrict__ dis,
                           const float* __restrict__ bias,
                           const float* __restrict__ Wn,   // 32x32 row-major, L1-hot
                           float* __restrict__ H2, int N){
  int tid = blockIdx.x * 256 + threadIdx.x;
  int n = tid >> 3, qw = tid & 7;
  if (n >= N) return;   // whole 8-lane group exits together (node-aligned)
  float4 v = agg_body(H, offsets, csr, dis, bias, n, qw);

  const float4* __restrict__ Wn4 = (const float4*)Wn;  // Wn4[k*8 + col4]
  float4 o = make_float4(0.f, 0.f, 0.f, 0.f);
  #pragma unroll
  for (int p = 0; p < 8; p++){
    float4 hp;
    hp.x = __shfl(v.x, p, 8);
    hp.y = __shfl(v.y, p, 8);
    hp.z = __shfl(v.z, p, 8);
    hp.w = __shfl(v.w, p, 8);
    float4 wa = Wn4[(4 * p + 0) * 8 + qw];
    float4 wb = Wn4[(4 * p + 1) * 8 + qw];
    float4 wc = Wn4[(4 * p + 2) * 8 + qw];
    float4 wd = Wn4[(4 * p + 3) * 8 + qw];
    o.x = fmaf(hp.x, wa.x, o.x); o.y = fmaf(hp.x, wa.y, o.y);
    o.z = fmaf(hp.x, wa.z, o.z); o.w = fmaf(hp.x, wa.w, o.w);
    o.x = fmaf(hp.y, wb.x, o.x); o.y = fmaf(hp.y, wb.y, o.y);
    o.z = fmaf(hp.y, wb.z, o.z); o.w = fmaf(hp.y, wb.w, o.w);
    o.x = fmaf(hp.z, wc.x, o.x); o.y = fmaf(hp.z, wc.y, o.y);
    o.z = fmaf(hp.z, wc.z, o.z); o.w = fmaf(hp.z, wc.w, o.w);
    o.x = fmaf(hp.w, wd.x, o.x); o.y = fmaf(hp.w, wd.y, o.y);
    o.z = fmaf(hp.w, wd.z, o.z); o.w = fmaf(hp.w, wd.w, o.w);
  }
  ((float4*)H2)[(size_t)n * 8 + qw] = o;
}

// ---------------- graph boundaries (batch is sorted) ----------------
__global__ void gstarts_kernel(const int* __restrict__ batch, int* __restrict__ gstarts,
                               int N, int G){
  int g = blockIdx.x * blockDim.x + threadIdx.x;
  if (g > G) return;
  int lo = 0, hi = N;
  while (lo < hi){ int mid = (lo + hi) >> 1; if (batch[mid] < g) lo = mid + 1; else hi = mid; }
  gstarts[g] = lo;
}

// ------- fused head v6: GPB=4 graphs / 256-thread block (64 threads = 1 wave per
//   graph). Resident-graphs/CU doubles again (16-wave/CU observation). Every phase
//   keeps its exact per-output FP accumulation chain; dense1 loops outi over
//   {lt, lt+64} with the same two-accumulator half-split; dense2 is the same
//   64-lane shuffle reduce. -> absmax unchanged. ---------
__global__ __launch_bounds__(256) void head_kernel(
    const float* __restrict__ A, const float* __restrict__ keys,
    const int* __restrict__ gstarts,
    const float* __restrict__ cw1, const float* __restrict__ cb1,
    const float* __restrict__ cw2, const float* __restrict__ cb2,
    const float* __restrict__ lw1, const float* __restrict__ lb1,
    const float* __restrict__ lw2, const float* __restrict__ lb2,
    float* __restrict__ out, int G){
  int t = threadIdx.x;
  int sub = t >> 6, lt = t & 63;    // wave w = graph w of this block
  int g = blockIdx.x * GPB + sub;

  __shared__ float w1s[16 * 32 * 5];   // 2560, shared by all graphs
  __shared__ float w2s[32 * 16 * 5];   // 2560, shared by all graphs
  __shared__ float bufA[GPB][960];
  __shared__ float bufB[GPB][416];
  __shared__ int   sel[GPB][SORTK];

  for (int i = t; i < 2560; i += 256) w1s[i] = cw1[i];
  for (int i = t; i < 2560; i += 256) w2s[i] = cw2[i];
  for (int i = lt; i < 960; i += 64) bufA[sub][i] = 0.f;

  bool valid = (g < G);
  int s = 0, c = 0;
  if (valid){ s = gstarts[g]; c = gstarts[g + 1] - s; }
  bool fast = valid && (c <= KCAP);
  if (fast)
    for (int i = lt; i < c; i += 64) bufB[sub][i] = keys[s + i];   // coalesced
  __syncthreads();

  // stable top-30 rank: key desc, index asc (bit-identical selection)
  if (valid){
    if (fast){
      for (int i = lt; i < c; i += 64){
        float ki = bufB[sub][i];
        int rank = 0;
        #pragma unroll 8
        for (int j = 0; j < c; j++){
          float kj = bufB[sub][j];
          rank += (kj > ki || (kj == ki && j < i)) ? 1 : 0;
        }
        if (rank < SORTK) sel[sub][rank] = i;
      }
    } else {
      for (int i = lt; i < c; i += 64){
        float ki = keys[s + i];
        int rank = 0;
        for (int j = 0; j < c; j++){
          float kj = keys[s + j];
          if (kj > ki || (kj == ki && j < i)){
            if (++rank >= SORTK) break;
          }
        }
        if (rank < SORTK) sel[sub][rank] = i;
      }
    }
  }
  __syncthreads();

  // gather selected rows into conv layout sin_[ch*30+pos]
  if (valid){
    int kk = c < SORTK ? c : SORTK;
    for (int q = lt; q < kk * 32; q += 64){
      int pos = q >> 5, ch = q & 31;
      bufA[sub][ch * 30 + pos] = A[(size_t)(s + sel[sub][pos]) * 32 + ch];
    }
  }
  __syncthreads();

  // conv1: (32,30) -> (16,26)
  if (valid){
    for (int q = lt; q < 16 * 26; q += 64){
      int o = q / 26, tt = q - o * 26;
      float acc = cb1[o];
      const float* wo = &w1s[o * 160];
      #pragma unroll 4
      for (int i = 0; i < 32; i++){
        const float* si = &bufA[sub][i * 30 + tt];
        #pragma unroll
        for (int k = 0; k < 5; k++) acc = fmaf(si[k], wo[i * 5 + k], acc);
      }
      bufB[sub][q] = fmaxf(acc, 0.f);
    }
  }
  __syncthreads();

  // conv2: (16,26) -> (32,22)
  if (valid){
    for (int q = lt; q < 32 * 22; q += 64){
      int o = q / 22, tt = q - o * 22;
      float acc = cb2[o];
      const float* wo = &w2s[o * 80];
      #pragma unroll 4
      for (int i = 0; i < 16; i++){
        const float* si = &bufB[sub][i * 26 + tt];
        #pragma unroll
        for (int k = 0; k < 5; k++) acc = fmaf(si[k], wo[i * 5 + k], acc);
      }
      bufA[sub][q] = fmaxf(acc, 0.f);
    }
  }
  __syncthreads();

  // dense1: 704 -> 128; each thread computes outputs {lt, lt+64} with the exact
  // two-accumulator half-split order: (lb1 + sum[0..351]) + (sum[352..703]), relu.
  if (valid){
    for (int outi = lt; outi < 128; outi += 64){
      float accA = lb1[outi];
      float accB = 0.f;
      #pragma unroll 8
      for (int j = 0; j < 352; j++)
        accA = fmaf(bufA[sub][j], lw1[(size_t)j * 128 + outi], accA);
      #pragma unroll 8
      for (int j = 352; j < 704; j++)
        accB = fmaf(bufA[sub][j], lw1[(size_t)j * 128 + outi], accB);
      bufB[sub][outi] = fmaxf(accA + accB, 0.f);
    }
  }
  __syncthreads();

  // dense2: 128 -> 1, one-wave shuffle reduce (each graph = exactly one wave)
  if (valid){
    float v = __fadd_rn(__fmul_rn(bufB[sub][lt], lw2[lt]),
                        __fmul_rn(bufB[sub][lt + 64], lw2[lt + 64]));
    #pragma unroll
    for (int o = 32; o > 0; o >>= 1) v += __shfl_xor(v, o, 64);
    if (lt == 0) out[g] = v + lb2[0];
  }
}

// ---------------- launch ----------------
extern "C" void kernel_launch(void* const* d_in, const int* in_sizes, int n_in,
                              void* d_out, int out_size, void* d_ws, size_t ws_size,
                              hipStream_t stream){
  const float* x     = (const float*)d_in[0];
  const int*   ei    = (const int*)  d_in[1];
  const int*   batch = (const int*)  d_in[2];
  const float* W1  = (const float*)d_in[4];
  const float* b1  = (const float*)d_in[5];
  const float* W2  = (const float*)d_in[6];
  const float* b2  = (const float*)d_in[7];
  const float* W3  = (const float*)d_in[8];
  const float* b3  = (const float*)d_in[9];
  const float* cw1 = (const float*)d_in[10];
  const float* cb1 = (const float*)d_in[11];
  const float* cw2 = (const float*)d_in[12];
  const float* cb2 = (const float*)d_in[13];
  const float* lw1 = (const float*)d_in[14];
  const float* lb1 = (const float*)d_in[15];
  const float* lw2 = (const float*)d_in[16];
  const float* lb2 = (const float*)d_in[17];

  int N = in_sizes[0] / 9;
  int E = in_sizes[1] / 2;
  int G = out_size;
  const int* srcs = ei;
  const int* dsts = ei + E;
  int NB = ceil_div_i(N, BNODES);
  int segsz = ceil_div_i(E, NSEG);

  char* base = (char*)d_ws;
  size_t off = 0;
  auto alloc = [&](size_t bytes) -> void* {
    off = (off + 255) & ~(size_t)255;
    void* r = base + off; off += bytes; return r;
  };
  float* dis    = (float*)alloc((size_t)N * 4);
  float* H      = (float*)alloc((size_t)N * 32 * 4);   // aliased as staging
  float* A      = (float*)alloc((size_t)N * 32 * 4);
  float* keyarr = (float*)alloc((size_t)N * 4);
  int*   offs   = (int*)alloc((size_t)(N + 1) * 4);
  int*   csr    = (int*)alloc((size_t)E * 4);
  int*   gst    = (int*)alloc((size_t)(G + 1) * 4);
  int*   hist   = (int*)alloc((size_t)NSEG * NB * 4);
  int*   segoff = (int*)alloc((size_t)NSEG * NB * 4);
  int*   btot   = (int*)alloc((size_t)NB * 4);
  int*   bbase  = (int*)alloc((size_t)(NB + 1) * 4);
  unsigned* staging = (unsigned*)H;
  (void)ws_size; (void)n_in;

  hist_kernel<<<NSEG, 1024, 0, stream>>>(dsts, hist, E, NB, segsz);
  segscanA<<<ceil_div_i(NB * 64, 256), 256, 0, stream>>>(hist, segoff, btot, NB, NSEG);
  segscanB<<<1, 1024, 0, stream>>>(btot, bbase, NB);
  scatter_kernel<<<NSEG, 1024, 0, stream>>>(dsts, segoff, bbase, staging, E, NB, segsz);
  bucket_sort_kernel<<<NB, 256, 0, stream>>>(bbase, staging, srcs, csr, offs, dis, N, NB, E);

  int ntm = ceil_div_i((long long)N * 32, 256);
  int nta = ceil_div_i((long long)N * 8, 256);
  // layer 1: H = x@W1 ; layer1 agg fused with matmul of W2 -> A holds next H
  node_matmul<9><<<ntm, 256, 0, stream>>>(x, W1, H, N);
  agg_mm_kernel<<<nta, 256, 0, stream>>>(H, offs, csr, dis, b1, W2, A, N);
  // layer 2: agg fused with matmul of W3 -> H holds next H
  agg_mm_kernel<<<nta, 256, 0, stream>>>(A, offs, csr, dis, b2, W3, H, N);
  // layer 3: plain agg -> A (+ sort keys) for the head
  agg_kernel<<<nta, 256, 0, stream>>>(H, offs, csr, dis, b3, A, keyarr, N);

  gstarts_kernel<<<ceil_div_i(G + 1, 256), 256, 0, stream>>>(batch, gst, N, G);
  head_kernel<<<ceil_div_i(G, GPB), 256, 0, stream>>>(A, keyarr, gst, cw1, cb1, cw2, cb2,
                                                      lw1, lb1, lw2, lb2, (float*)d_out, G);
}

// Round 14
// 485.290 us; speedup vs baseline: 1.0543x; 1.0543x over previous
//
#include <hip/hip_runtime.h>

typedef unsigned long long ull;

#define HIDDEN 32
#define SORTK 30
#define KCAP 256              // max nodes/graph fast path (mean 122, sd 11; 12 sigma)
#define GPB 2                 // graphs per block (shared weight stage)
#define BSH 7                 // 128 nodes per bucket
#define BNODES (1 << BSH)
#define BCAP 1536
#define HMAX 2048
#define NSEG 256
#define EID_BITS 22           // E = 2.5M < 4.19M
#define EID_MASK ((1u << EID_BITS) - 1)

static inline int ceil_div_i(long long a, int b){ return (int)((a + b - 1) / b); }

// ---------------- phase 1: per-segment LDS histogram ----------------
__global__ __launch_bounds__(1024) void hist_kernel(const int* __restrict__ dsts,
                                                    int* __restrict__ hist,
                                                    int E, int NB, int segsz){
  __shared__ int h[HMAX];
  for (int i = threadIdx.x; i < NB; i += 1024) h[i] = 0;
  __syncthreads();
  int seg = blockIdx.x;
  int e0 = seg * segsz;
  int e1 = e0 + segsz; if (e1 > E) e1 = E;
  for (int e = e0 + threadIdx.x; e < e1; e += 1024)
    atomicAdd(&h[dsts[e] >> BSH], 1);
  __syncthreads();
  for (int i = threadIdx.x; i < NB; i += 1024) hist[seg * NB + i] = h[i];
}

// ---------------- phase 2a: per-bucket prefix over segments (1 wave / bucket) -------
__global__ __launch_bounds__(256) void segscanA(const int* __restrict__ hist,
                                                int* __restrict__ segoff,
                                                int* __restrict__ btot,
                                                int NB, int S){
  int wv = (blockIdx.x * 256 + threadIdx.x) >> 6;
  int lane = threadIdx.x & 63;
  if (wv >= NB) return;
  int b = wv;
  int run_base = 0;
  for (int chunk = 0; chunk < S; chunk += 64){
    int s = chunk + lane;
    int v = (s < S) ? hist[(size_t)s * NB + b] : 0;
    int x = v;
    #pragma unroll
    for (int o = 1; o < 64; o <<= 1){ int y = __shfl_up(x, o, 64); if (lane >= o) x += y; }
    if (s < S) segoff[(size_t)s * NB + b] = run_base + x - v;
    run_base += __shfl(x, 63, 64);
  }
  if (lane == 0) btot[b] = run_base;
}

// ---------------- phase 2b: exclusive scan of bucket totals (1 block) ----------------
__global__ __launch_bounds__(1024) void segscanB(const int* __restrict__ btot,
                                                 int* __restrict__ bbase, int NB){
  int t = threadIdx.x;
  int b0 = t * 2, b1 = t * 2 + 1;
  int v0 = (b0 < NB) ? btot[b0] : 0;
  int v1 = (b1 < NB) ? btot[b1] : 0;
  int pair = v0 + v1;
  int lane = t & 63, wid = t >> 6;
  int x = pair;
  for (int o = 1; o < 64; o <<= 1){ int y = __shfl_up(x, o, 64); if (lane >= o) x += y; }
  __shared__ int wsum[16]; __shared__ int woff[16];
  if (lane == 63) wsum[wid] = x;
  __syncthreads();
  if (t == 0){ int run = 0; for (int w = 0; w < 16; w++){ woff[w] = run; run += wsum[w]; } }
  __syncthreads();
  int excl = x - pair + woff[wid];
  if (b0 < NB) bbase[b0] = excl;
  if (b1 < NB) bbase[b1] = excl + v0;
}

// ---------------- phase 3: scatter 32-bit key (ld,eid), block-private regions ------
// key = (local_node << 22) | eid ; unsigned ascending == (ld, eid) ascending.
// src payload is recovered later as srcs[eid] (10 MB L2/L3-resident).
__global__ __launch_bounds__(1024) void scatter_kernel(const int* __restrict__ dsts,
                                                       const int* __restrict__ segoff,
                                                       const int* __restrict__ bbase,
                                                       unsigned* __restrict__ staging,
                                                       int E, int NB, int segsz){
  __shared__ int cur[HMAX];
  int seg = blockIdx.x;
  for (int i = threadIdx.x; i < NB; i += 1024) cur[i] = segoff[(size_t)seg * NB + i] + bbase[i];
  __syncthreads();
  int e0 = seg * segsz;
  int e1 = e0 + segsz; if (e1 > E) e1 = E;
  for (int e = e0 + threadIdx.x; e < e1; e += 1024){
    int d = dsts[e];
    int slot = atomicAdd(&cur[d >> BSH], 1);
    staging[slot] = ((unsigned)(d & (BNODES - 1)) << EID_BITS) | (unsigned)e;
  }
}

// ---------------- phase 4: per-bucket LDS bin + parallel rank -> CSR ----------------
// 256 threads; edge loops stride 256, node sections guard t<128. All cross-wave
// LDS dependencies synchronized with UNIFORM __syncthreads().
__global__ __launch_bounds__(256) void bucket_sort_kernel(
    const int* __restrict__ bbase, const unsigned* __restrict__ staging,
    const int* __restrict__ srcs,
    int* __restrict__ csr, int* __restrict__ offs,
    float* __restrict__ dis, int N, int NB, int E){
  __shared__ unsigned ebuf[BCAP];
  __shared__ unsigned obuf[BCAP];
  __shared__ int cnt[BNODES];
  __shared__ int cur[BNODES];
  __shared__ int base0[BNODES];
  __shared__ int w0tot;
  int b = blockIdx.x, t = threadIdx.x;
  int n0 = b << BSH;
  int n1 = n0 + BNODES; if (n1 > N) n1 = N;
  int gbeg = bbase[b];
  int gend = (b + 1 < NB) ? bbase[b + 1] : E;
  int cnt_all = gend - gbeg;
  if (t < BNODES) cnt[t] = 0;
  __syncthreads();

  if (cnt_all <= BCAP){
    for (int i = t; i < cnt_all; i += 256){
      unsigned k = staging[gbeg + i];
      ebuf[i] = k;
      atomicAdd(&cnt[k >> EID_BITS], 1);
    }
    __syncthreads();
    int v = 0, x = 0;
    if (t < BNODES){
      v = cnt[t];
      int lane = t & 63, wid = t >> 6;
      x = v;
      for (int o = 1; o < 64; o <<= 1){ int y = __shfl_up(x, o, 64); if (lane >= o) x += y; }
      if (wid == 0 && lane == 63) w0tot = x;
    }
    __syncthreads();   // uniform: makes w0tot visible to wave 1
    if (t < BNODES){
      int wid = t >> 6;
      int ls = x - v + (wid ? w0tot : 0);
      cur[t] = ls;
      base0[t] = ls;
      int n = n0 + t;
      if (n < n1){
        float dd = (float)v + 1.0f;
        dis[n]  = __fdiv_rn(1.0f, __fsqrt_rn(dd));
        offs[n] = gbeg + ls;
      }
    }
    __syncthreads();
    for (int i = t; i < cnt_all; i += 256){
      unsigned k = ebuf[i];
      int pos = atomicAdd(&cur[k >> EID_BITS], 1);
      obuf[pos] = k;
    }
    __syncthreads();
    for (int i = t; i < cnt_all; i += 256){
      unsigned k = obuf[i];
      int nd = (int)(k >> EID_BITS);
      int base = base0[nd];
      int vn = cnt[nd];
      int r = 0;
      for (int j = 0; j < vn; j++) r += (obuf[base + j] < k) ? 1 : 0;
      csr[gbeg + base + r] = srcs[k & EID_MASK];
    }
  } else {
    // statistically unreachable fallback (correct, slow)
    if (t < BNODES){
      int n = n0 + t;
      int deg = 0;
      if (n < n1){
        for (int i = gbeg; i < gend; i++) if ((int)(staging[i] >> EID_BITS) == t) deg++;
        float dd = (float)deg + 1.0f;
        dis[n] = __fdiv_rn(1.0f, __fsqrt_rn(dd));
      }
      cnt[t] = (n < n1) ? deg : 0;
    }
    __syncthreads();
    if (t < BNODES){
      int n = n0 + t;
      if (n < n1){
        int deg = cnt[t];
        int ls = gbeg; for (int q = 0; q < t; q++) ls += cnt[q];
        offs[n] = ls;
        unsigned prev = 0;
        for (int o = 0; o < deg; o++){
          unsigned best = 0xFFFFFFFFu;
          for (int i = gbeg; i < gend; i++){
            unsigned k = staging[i];
            if ((int)(k >> EID_BITS) == t && (o == 0 || k > prev) && k < best) best = k;
          }
          csr[ls + o] = srcs[best & EID_MASK]; prev = best;
        }
      }
    }
  }
  if (b == 0 && t == 0) offs[N] = E;
}

// ---------------- per-node matmul h = x @ W ----------------
template<int K>
__global__ void node_matmul(const float* __restrict__ xin, const float* __restrict__ W,
                            float* __restrict__ H, int N){
  __shared__ float Ws[K * 32];
  for (int i = threadIdx.x; i < K * 32; i += blockDim.x) Ws[i] = W[i];
  __syncthreads();
  int tid = blockIdx.x * blockDim.x + threadIdx.x;
  int n = tid >> 5, c = tid & 31;
  if (n >= N) return;
  const float* xr = xin + (size_t)n * K;
  float acc = 0.f;
  #pragma unroll
  for (int k = 0; k < K; k++) acc = fmaf(xr[k], Ws[k * 32 + c], acc);
  H[(size_t)n * 32 + c] = acc;
}

// ---------------- GCN aggregation helpers ----------------
__device__ __forceinline__ float4 acc_edge(float4 a, float4 h, float w){
  a.x = __fadd_rn(a.x, __fmul_rn(h.x, w));
  a.y = __fadd_rn(a.y, __fmul_rn(h.y, w));
  a.z = __fadd_rn(a.z, __fmul_rn(h.z, w));
  a.w = __fadd_rn(a.w, __fmul_rn(h.w, w));
  return a;
}

// core agg body: returns v = relu(agg + selfterm + bias) for this lane's quad
__device__ __forceinline__ float4 agg_body(const float* __restrict__ H,
                                           const int* __restrict__ offsets,
                                           const int* __restrict__ csr,
                                           const float* __restrict__ dis,
                                           const float* __restrict__ bias,
                                           int n, int qw){
  const float4* __restrict__ H4 = (const float4*)H;
  float dn = dis[n];
  int s = offsets[n], e = offsets[n + 1];
  float4 acc = make_float4(0.f, 0.f, 0.f, 0.f);
  int i = s;
  for (; i + 8 <= e; i += 8){
    int s0 = csr[i],   s1 = csr[i+1], s2 = csr[i+2], s3 = csr[i+3];
    int s4 = csr[i+4], s5 = csr[i+5], s6 = csr[i+6], s7 = csr[i+7];
    float4 h0 = H4[(size_t)s0 * 8 + qw];
    float4 h1 = H4[(size_t)s1 * 8 + qw];
    float4 h2 = H4[(size_t)s2 * 8 + qw];
    float4 h3 = H4[(size_t)s3 * 8 + qw];
    float4 h4 = H4[(size_t)s4 * 8 + qw];
    float4 h5 = H4[(size_t)s5 * 8 + qw];
    float4 h6 = H4[(size_t)s6 * 8 + qw];
    float4 h7 = H4[(size_t)s7 * 8 + qw];
    float w0 = __fmul_rn(dis[s0], dn), w1 = __fmul_rn(dis[s1], dn);
    float w2 = __fmul_rn(dis[s2], dn), w3 = __fmul_rn(dis[s3], dn);
    float w4 = __fmul_rn(dis[s4], dn), w5 = __fmul_rn(dis[s5], dn);
    float w6 = __fmul_rn(dis[s6], dn), w7 = __fmul_rn(dis[s7], dn);
    acc = acc_edge(acc, h0, w0);
    acc = acc_edge(acc, h1, w1);
    acc = acc_edge(acc, h2, w2);
    acc = acc_edge(acc, h3, w3);
    acc = acc_edge(acc, h4, w4);
    acc = acc_edge(acc, h5, w5);
    acc = acc_edge(acc, h6, w6);
    acc = acc_edge(acc, h7, w7);
  }
  for (; i < e; i++){
    int sr = csr[i];
    float w = __fmul_rn(dis[sr], dn);
    acc = acc_edge(acc, H4[(size_t)sr * 8 + qw], w);
  }
  float4 hn = H4[(size_t)n * 8 + qw];
  float sw = __fmul_rn(dn, dn);
  float4 bb = ((const float4*)bias)[qw];
  float4 v;
  v.x = fmaxf(__fadd_rn(__fadd_rn(acc.x, __fmul_rn(hn.x, sw)), bb.x), 0.f);
  v.y = fmaxf(__fadd_rn(__fadd_rn(acc.y, __fmul_rn(hn.y, sw)), bb.y), 0.f);
  v.z = fmaxf(__fadd_rn(__fadd_rn(acc.z, __fmul_rn(hn.z, sw)), bb.z), 0.f);
  v.w = fmaxf(__fadd_rn(__fadd_rn(acc.w, __fmul_rn(hn.w, sw)), bb.w), 0.f);
  return v;
}

// final-layer agg: writes A (+ sort key)
__global__ __launch_bounds__(256) void agg_kernel(const float* __restrict__ H,
                           const int* __restrict__ offsets,
                           const int* __restrict__ csr, const float* __restrict__ dis,
                           const float* __restrict__ bias, float* __restrict__ A,
                           float* __restrict__ keyout, int N){
  int tid = blockIdx.x * 256 + threadIdx.x;
  int n = tid >> 3, qw = tid & 7;
  if (n >= N) return;
  float4 v = agg_body(H, offsets, csr, dis, bias, n, qw);
  ((float4*)A)[(size_t)n * 8 + qw] = v;
  if (keyout != nullptr && qw == 7) keyout[n] = v.w;
}

// fused agg + next-layer matmul (bit-identical to node_matmul<32>, k ascending)
__global__ __launch_bounds__(256) void agg_mm_kernel(const float* __restrict__ H,
                           const int* __restrict__ offsets,
                           const int* __restrict__ csr, const float* __restrict__ dis,
                           const float* __restrict__ bias,
                           const float* __restrict__ Wn,   // 32x32 row-major, L1-hot
                           float* __restrict__ H2, int N){
  int tid = blockIdx.x * 256 + threadIdx.x;
  int n = tid >> 3, qw = tid & 7;
  if (n >= N) return;   // whole 8-lane group exits together (node-aligned)
  float4 v = agg_body(H, offsets, csr, dis, bias, n, qw);

  const float4* __restrict__ Wn4 = (const float4*)Wn;  // Wn4[k*8 + col4]
  float4 o = make_float4(0.f, 0.f, 0.f, 0.f);
  #pragma unroll
  for (int p = 0; p < 8; p++){
    float4 hp;
    hp.x = __shfl(v.x, p, 8);
    hp.y = __shfl(v.y, p, 8);
    hp.z = __shfl(v.z, p, 8);
    hp.w = __shfl(v.w, p, 8);
    float4 wa = Wn4[(4 * p + 0) * 8 + qw];
    float4 wb = Wn4[(4 * p + 1) * 8 + qw];
    float4 wc = Wn4[(4 * p + 2) * 8 + qw];
    float4 wd = Wn4[(4 * p + 3) * 8 + qw];
    o.x = fmaf(hp.x, wa.x, o.x); o.y = fmaf(hp.x, wa.y, o.y);
    o.z = fmaf(hp.x, wa.z, o.z); o.w = fmaf(hp.x, wa.w, o.w);
    o.x = fmaf(hp.y, wb.x, o.x); o.y = fmaf(hp.y, wb.y, o.y);
    o.z = fmaf(hp.y, wb.z, o.z); o.w = fmaf(hp.y, wb.w, o.w);
    o.x = fmaf(hp.z, wc.x, o.x); o.y = fmaf(hp.z, wc.y, o.y);
    o.z = fmaf(hp.z, wc.z, o.z); o.w = fmaf(hp.z, wc.w, o.w);
    o.x = fmaf(hp.w, wd.x, o.x); o.y = fmaf(hp.w, wd.y, o.y);
    o.z = fmaf(hp.w, wd.z, o.z); o.w = fmaf(hp.w, wd.w, o.w);
  }
  ((float4*)H2)[(size_t)n * 8 + qw] = o;
}

// ---------------- graph boundaries (batch is sorted) ----------------
__global__ void gstarts_kernel(const int* __restrict__ batch, int* __restrict__ gstarts,
                               int N, int G){
  int g = blockIdx.x * blockDim.x + threadIdx.x;
  if (g > G) return;
  int lo = 0, hi = N;
  while (lo < hi){ int mid = (lo + hi) >> 1; if (batch[mid] < g) lo = mid + 1; else hi = mid; }
  gstarts[g] = lo;
}

// ------- fused head v5 (measured optimum of the graphs-per-wave family):
//   GPB=2 / 256-thread block, 128 threads = 2 waves per graph. v4 (4 waves/graph)
//   and v6 (1 wave/graph, LDS-capped occupancy collapse) both measured slower. ------
__global__ __launch_bounds__(256) void head_kernel(
    const float* __restrict__ A, const float* __restrict__ keys,
    const int* __restrict__ gstarts,
    const float* __restrict__ cw1, const float* __restrict__ cb1,
    const float* __restrict__ cw2, const float* __restrict__ cb2,
    const float* __restrict__ lw1, const float* __restrict__ lb1,
    const float* __restrict__ lw2, const float* __restrict__ lb2,
    float* __restrict__ out, int G){
  int t = threadIdx.x;
  int sub = t >> 7, lt = t & 127;    // waves 0-1 = graph 0, waves 2-3 = graph 1
  int g = blockIdx.x * GPB + sub;

  __shared__ float w1s[16 * 32 * 5];   // 2560, shared by both graphs
  __shared__ float w2s[32 * 16 * 5];   // 2560, shared by both graphs
  __shared__ float bufA[GPB][960];
  __shared__ float bufB[GPB][416];
  __shared__ int   sel[GPB][SORTK];

  for (int i = t; i < 2560; i += 256) w1s[i] = cw1[i];
  for (int i = t; i < 2560; i += 256) w2s[i] = cw2[i];
  for (int i = lt; i < 960; i += 128) bufA[sub][i] = 0.f;

  bool valid = (g < G);
  int s = 0, c = 0;
  if (valid){ s = gstarts[g]; c = gstarts[g + 1] - s; }
  bool fast = valid && (c <= KCAP);
  if (fast)
    for (int i = lt; i < c; i += 128) bufB[sub][i] = keys[s + i];   // coalesced
  __syncthreads();

  // stable top-30 rank: key desc, index asc (bit-identical selection)
  if (valid){
    if (fast){
      for (int i = lt; i < c; i += 128){
        float ki = bufB[sub][i];
        int rank = 0;
        #pragma unroll 8
        for (int j = 0; j < c; j++){
          float kj = bufB[sub][j];
          rank += (kj > ki || (kj == ki && j < i)) ? 1 : 0;
        }
        if (rank < SORTK) sel[sub][rank] = i;
      }
    } else {
      for (int i = lt; i < c; i += 128){
        float ki = keys[s + i];
        int rank = 0;
        for (int j = 0; j < c; j++){
          float kj = keys[s + j];
          if (kj > ki || (kj == ki && j < i)){
            if (++rank >= SORTK) break;
          }
        }
        if (rank < SORTK) sel[sub][rank] = i;
      }
    }
  }
  __syncthreads();

  // gather selected rows into conv layout sin_[ch*30+pos]
  if (valid){
    int kk = c < SORTK ? c : SORTK;
    for (int q = lt; q < kk * 32; q += 128){
      int pos = q >> 5, ch = q & 31;
      bufA[sub][ch * 30 + pos] = A[(size_t)(s + sel[sub][pos]) * 32 + ch];
    }
  }
  __syncthreads();

  // conv1: (32,30) -> (16,26)
  if (valid){
    for (int q = lt; q < 16 * 26; q += 128){
      int o = q / 26, tt = q - o * 26;
      float acc = cb1[o];
      const float* wo = &w1s[o * 160];
      #pragma unroll 4
      for (int i = 0; i < 32; i++){
        const float* si = &bufA[sub][i * 30 + tt];
        #pragma unroll
        for (int k = 0; k < 5; k++) acc = fmaf(si[k], wo[i * 5 + k], acc);
      }
      bufB[sub][q] = fmaxf(acc, 0.f);
    }
  }
  __syncthreads();

  // conv2: (16,26) -> (32,22)
  if (valid){
    for (int q = lt; q < 32 * 22; q += 128){
      int o = q / 22, tt = q - o * 22;
      float acc = cb2[o];
      const float* wo = &w2s[o * 80];
      #pragma unroll 4
      for (int i = 0; i < 16; i++){
        const float* si = &bufB[sub][i * 26 + tt];
        #pragma unroll
        for (int k = 0; k < 5; k++) acc = fmaf(si[k], wo[i * 5 + k], acc);
      }
      bufA[sub][q] = fmaxf(acc, 0.f);
    }
  }
  __syncthreads();

  // dense1: 704 -> 128; one thread per output, two accumulators preserving v4's
  // half-split FP order exactly: (lb1 + sum[0..351]) + (sum[352..703]), then relu.
  if (valid){
    int outi = lt;
    float accA = lb1[outi];
    float accB = 0.f;
    #pragma unroll 8
    for (int j = 0; j < 352; j++)
      accA = fmaf(bufA[sub][j], lw1[(size_t)j * 128 + outi], accA);
    #pragma unroll 8
    for (int j = 352; j < 704; j++)
      accB = fmaf(bufA[sub][j], lw1[(size_t)j * 128 + outi], accB);
    bufB[sub][outi] = fmaxf(accA + accB, 0.f);
  }
  __syncthreads();

  // dense2: 128 -> 1, one-wave shuffle reduce (lt<64 is a full wave in each sub)
  if (valid && lt < 64){
    float v = __fadd_rn(__fmul_rn(bufB[sub][lt], lw2[lt]),
                        __fmul_rn(bufB[sub][lt + 64], lw2[lt + 64]));
    #pragma unroll
    for (int o = 32; o > 0; o >>= 1) v += __shfl_xor(v, o, 64);
    if (lt == 0) out[g] = v + lb2[0];
  }
}

// ---------------- launch ----------------
extern "C" void kernel_launch(void* const* d_in, const int* in_sizes, int n_in,
                              void* d_out, int out_size, void* d_ws, size_t ws_size,
                              hipStream_t stream){
  const float* x     = (const float*)d_in[0];
  const int*   ei    = (const int*)  d_in[1];
  const int*   batch = (const int*)  d_in[2];
  const float* W1  = (const float*)d_in[4];
  const float* b1  = (const float*)d_in[5];
  const float* W2  = (const float*)d_in[6];
  const float* b2  = (const float*)d_in[7];
  const float* W3  = (const float*)d_in[8];
  const float* b3  = (const float*)d_in[9];
  const float* cw1 = (const float*)d_in[10];
  const float* cb1 = (const float*)d_in[11];
  const float* cw2 = (const float*)d_in[12];
  const float* cb2 = (const float*)d_in[13];
  const float* lw1 = (const float*)d_in[14];
  const float* lb1 = (const float*)d_in[15];
  const float* lw2 = (const float*)d_in[16];
  const float* lb2 = (const float*)d_in[17];

  int N = in_sizes[0] / 9;
  int E = in_sizes[1] / 2;
  int G = out_size;
  const int* srcs = ei;
  const int* dsts = ei + E;
  int NB = ceil_div_i(N, BNODES);
  int segsz = ceil_div_i(E, NSEG);

  char* base = (char*)d_ws;
  size_t off = 0;
  auto alloc = [&](size_t bytes) -> void* {
    off = (off + 255) & ~(size_t)255;
    void* r = base + off; off += bytes; return r;
  };
  float* dis    = (float*)alloc((size_t)N * 4);
  float* H      = (float*)alloc((size_t)N * 32 * 4);   // aliased as staging
  float* A      = (float*)alloc((size_t)N * 32 * 4);
  float* keyarr = (float*)alloc((size_t)N * 4);
  int*   offs   = (int*)alloc((size_t)(N + 1) * 4);
  int*   csr    = (int*)alloc((size_t)E * 4);
  int*   gst    = (int*)alloc((size_t)(G + 1) * 4);
  int*   hist   = (int*)alloc((size_t)NSEG * NB * 4);
  int*   segoff = (int*)alloc((size_t)NSEG * NB * 4);
  int*   btot   = (int*)alloc((size_t)NB * 4);
  int*   bbase  = (int*)alloc((size_t)(NB + 1) * 4);
  unsigned* staging = (unsigned*)H;
  (void)ws_size; (void)n_in;

  hist_kernel<<<NSEG, 1024, 0, stream>>>(dsts, hist, E, NB, segsz);
  segscanA<<<ceil_div_i(NB * 64, 256), 256, 0, stream>>>(hist, segoff, btot, NB, NSEG);
  segscanB<<<1, 1024, 0, stream>>>(btot, bbase, NB);
  scatter_kernel<<<NSEG, 1024, 0, stream>>>(dsts, segoff, bbase, staging, E, NB, segsz);
  bucket_sort_kernel<<<NB, 256, 0, stream>>>(bbase, staging, srcs, csr, offs, dis, N, NB, E);

  int ntm = ceil_div_i((long long)N * 32, 256);
  int nta = ceil_div_i((long long)N * 8, 256);
  // layer 1: H = x@W1 ; layer1 agg fused with matmul of W2 -> A holds next H
  node_matmul<9><<<ntm, 256, 0, stream>>>(x, W1, H, N);
  agg_mm_kernel<<<nta, 256, 0, stream>>>(H, offs, csr, dis, b1, W2, A, N);
  // layer 2: agg fused with matmul of W3 -> H holds next H
  agg_mm_kernel<<<nta, 256, 0, stream>>>(A, offs, csr, dis, b2, W3, H, N);
  // layer 3: plain agg -> A (+ sort keys) for the head
  agg_kernel<<<nta, 256, 0, stream>>>(H, offs, csr, dis, b3, A, keyarr, N);

  gstarts_kernel<<<ceil_div_i(G + 1, 256), 256, 0, stream>>>(batch, gst, N, G);
  head_kernel<<<ceil_div_i(G, GPB), 256, 0, stream>>>(A, keyarr, gst, cw1, cb1, cw2, cb2,
                                                      lw1, lb1, lw2, lb2, (float*)d_out, G);
}

// Round 15
// 464.575 us; speedup vs baseline: 1.1013x; 1.0446x over previous
//
#include <hip/hip_runtime.h>

typedef unsigned long long ull;

#define HIDDEN 32
#define SORTK 30
#define KCAP 256              // max nodes/graph fast path (mean 122, sd 11; 12 sigma)
#define GPB 2                 // graphs per block (shared weight stage)
#define BSH 7                 // 128 nodes per bucket
#define BNODES (1 << BSH)
#define BCAP 1536
#define HMAX 2048
#define NSEG 256
#define EID_BITS 22           // E = 2.5M < 4.19M
#define EID_MASK ((1u << EID_BITS) - 1)

static inline int ceil_div_i(long long a, int b){ return (int)((a + b - 1) / b); }

// ---------------- phase 1: per-segment LDS histogram ----------------
__global__ __launch_bounds__(1024) void hist_kernel(const int* __restrict__ dsts,
                                                    int* __restrict__ hist,
                                                    int E, int NB, int segsz){
  __shared__ int h[HMAX];
  for (int i = threadIdx.x; i < NB; i += 1024) h[i] = 0;
  __syncthreads();
  int seg = blockIdx.x;
  int e0 = seg * segsz;
  int e1 = e0 + segsz; if (e1 > E) e1 = E;
  for (int e = e0 + threadIdx.x; e < e1; e += 1024)
    atomicAdd(&h[dsts[e] >> BSH], 1);
  __syncthreads();
  for (int i = threadIdx.x; i < NB; i += 1024) hist[seg * NB + i] = h[i];
}

// ---------------- phase 2a: per-bucket prefix over segments (1 wave / bucket) -------
__global__ __launch_bounds__(256) void segscanA(const int* __restrict__ hist,
                                                int* __restrict__ segoff,
                                                int* __restrict__ btot,
                                                int NB, int S){
  int wv = (blockIdx.x * 256 + threadIdx.x) >> 6;
  int lane = threadIdx.x & 63;
  if (wv >= NB) return;
  int b = wv;
  int run_base = 0;
  for (int chunk = 0; chunk < S; chunk += 64){
    int s = chunk + lane;
    int v = (s < S) ? hist[(size_t)s * NB + b] : 0;
    int x = v;
    #pragma unroll
    for (int o = 1; o < 64; o <<= 1){ int y = __shfl_up(x, o, 64); if (lane >= o) x += y; }
    if (s < S) segoff[(size_t)s * NB + b] = run_base + x - v;
    run_base += __shfl(x, 63, 64);
  }
  if (lane == 0) btot[b] = run_base;
}

// ---------------- phase 2b: exclusive scan of bucket totals (1 block) ----------------
__global__ __launch_bounds__(1024) void segscanB(const int* __restrict__ btot,
                                                 int* __restrict__ bbase, int NB){
  int t = threadIdx.x;
  int b0 = t * 2, b1 = t * 2 + 1;
  int v0 = (b0 < NB) ? btot[b0] : 0;
  int v1 = (b1 < NB) ? btot[b1] : 0;
  int pair = v0 + v1;
  int lane = t & 63, wid = t >> 6;
  int x = pair;
  for (int o = 1; o < 64; o <<= 1){ int y = __shfl_up(x, o, 64); if (lane >= o) x += y; }
  __shared__ int wsum[16]; __shared__ int woff[16];
  if (lane == 63) wsum[wid] = x;
  __syncthreads();
  if (t == 0){ int run = 0; for (int w = 0; w < 16; w++){ woff[w] = run; run += wsum[w]; } }
  __syncthreads();
  int excl = x - pair + woff[wid];
  if (b0 < NB) bbase[b0] = excl;
  if (b1 < NB) bbase[b1] = excl + v0;
}

// ---------------- phase 3: scatter 32-bit key (ld,eid), block-private regions ------
// key = (local_node << 22) | eid ; unsigned ascending == (ld, eid) ascending.
// src payload is recovered later as srcs[eid] (10 MB L2/L3-resident).
__global__ __launch_bounds__(1024) void scatter_kernel(const int* __restrict__ dsts,
                                                       const int* __restrict__ segoff,
                                                       const int* __restrict__ bbase,
                                                       unsigned* __restrict__ staging,
                                                       int E, int NB, int segsz){
  __shared__ int cur[HMAX];
  int seg = blockIdx.x;
  for (int i = threadIdx.x; i < NB; i += 1024) cur[i] = segoff[(size_t)seg * NB + i] + bbase[i];
  __syncthreads();
  int e0 = seg * segsz;
  int e1 = e0 + segsz; if (e1 > E) e1 = E;
  for (int e = e0 + threadIdx.x; e < e1; e += 1024){
    int d = dsts[e];
    int slot = atomicAdd(&cur[d >> BSH], 1);
    staging[slot] = ((unsigned)(d & (BNODES - 1)) << EID_BITS) | (unsigned)e;
  }
}

// ---------------- phase 4: per-bucket LDS bin + parallel rank -> CSR ----------------
// 256 threads; edge loops stride 256, node sections guard t<128. All cross-wave
// LDS dependencies synchronized with UNIFORM __syncthreads().
__global__ __launch_bounds__(256) void bucket_sort_kernel(
    const int* __restrict__ bbase, const unsigned* __restrict__ staging,
    const int* __restrict__ srcs,
    int* __restrict__ csr, int* __restrict__ offs,
    float* __restrict__ dis, int N, int NB, int E){
  __shared__ unsigned ebuf[BCAP];
  __shared__ unsigned obuf[BCAP];
  __shared__ int cnt[BNODES];
  __shared__ int cur[BNODES];
  __shared__ int base0[BNODES];
  __shared__ int w0tot;
  int b = blockIdx.x, t = threadIdx.x;
  int n0 = b << BSH;
  int n1 = n0 + BNODES; if (n1 > N) n1 = N;
  int gbeg = bbase[b];
  int gend = (b + 1 < NB) ? bbase[b + 1] : E;
  int cnt_all = gend - gbeg;
  if (t < BNODES) cnt[t] = 0;
  __syncthreads();

  if (cnt_all <= BCAP){
    for (int i = t; i < cnt_all; i += 256){
      unsigned k = staging[gbeg + i];
      ebuf[i] = k;
      atomicAdd(&cnt[k >> EID_BITS], 1);
    }
    __syncthreads();
    int v = 0, x = 0;
    if (t < BNODES){
      v = cnt[t];
      int lane = t & 63, wid = t >> 6;
      x = v;
      for (int o = 1; o < 64; o <<= 1){ int y = __shfl_up(x, o, 64); if (lane >= o) x += y; }
      if (wid == 0 && lane == 63) w0tot = x;
    }
    __syncthreads();   // uniform: makes w0tot visible to wave 1
    if (t < BNODES){
      int wid = t >> 6;
      int ls = x - v + (wid ? w0tot : 0);
      cur[t] = ls;
      base0[t] = ls;
      int n = n0 + t;
      if (n < n1){
        float dd = (float)v + 1.0f;
        dis[n]  = __fdiv_rn(1.0f, __fsqrt_rn(dd));
        offs[n] = gbeg + ls;
      }
    }
    __syncthreads();
    for (int i = t; i < cnt_all; i += 256){
      unsigned k = ebuf[i];
      int pos = atomicAdd(&cur[k >> EID_BITS], 1);
      obuf[pos] = k;
    }
    __syncthreads();
    for (int i = t; i < cnt_all; i += 256){
      unsigned k = obuf[i];
      int nd = (int)(k >> EID_BITS);
      int base = base0[nd];
      int vn = cnt[nd];
      int r = 0;
      for (int j = 0; j < vn; j++) r += (obuf[base + j] < k) ? 1 : 0;
      csr[gbeg + base + r] = srcs[k & EID_MASK];
    }
  } else {
    // statistically unreachable fallback (correct, slow)
    if (t < BNODES){
      int n = n0 + t;
      int deg = 0;
      if (n < n1){
        for (int i = gbeg; i < gend; i++) if ((int)(staging[i] >> EID_BITS) == t) deg++;
        float dd = (float)deg + 1.0f;
        dis[n] = __fdiv_rn(1.0f, __fsqrt_rn(dd));
      }
      cnt[t] = (n < n1) ? deg : 0;
    }
    __syncthreads();
    if (t < BNODES){
      int n = n0 + t;
      if (n < n1){
        int deg = cnt[t];
        int ls = gbeg; for (int q = 0; q < t; q++) ls += cnt[q];
        offs[n] = ls;
        unsigned prev = 0;
        for (int o = 0; o < deg; o++){
          unsigned best = 0xFFFFFFFFu;
          for (int i = gbeg; i < gend; i++){
            unsigned k = staging[i];
            if ((int)(k >> EID_BITS) == t && (o == 0 || k > prev) && k < best) best = k;
          }
          csr[ls + o] = srcs[best & EID_MASK]; prev = best;
        }
      }
    }
  }
  if (b == 0 && t == 0) offs[N] = E;
}

// ---------------- per-node matmul h = x @ W ----------------
template<int K>
__global__ void node_matmul(const float* __restrict__ xin, const float* __restrict__ W,
                            float* __restrict__ H, int N){
  __shared__ float Ws[K * 32];
  for (int i = threadIdx.x; i < K * 32; i += blockDim.x) Ws[i] = W[i];
  __syncthreads();
  int tid = blockIdx.x * blockDim.x + threadIdx.x;
  int n = tid >> 5, c = tid & 31;
  if (n >= N) return;
  const float* xr = xin + (size_t)n * K;
  float acc = 0.f;
  #pragma unroll
  for (int k = 0; k < K; k++) acc = fmaf(xr[k], Ws[k * 32 + c], acc);
  H[(size_t)n * 32 + c] = acc;
}

// ---------------- GCN aggregation helpers ----------------
__device__ __forceinline__ float4 acc_edge(float4 a, float4 h, float w){
  a.x = __fadd_rn(a.x, __fmul_rn(h.x, w));
  a.y = __fadd_rn(a.y, __fmul_rn(h.y, w));
  a.z = __fadd_rn(a.z, __fmul_rn(h.z, w));
  a.w = __fadd_rn(a.w, __fmul_rn(h.w, w));
  return a;
}

// core agg body: returns v = relu(agg + selfterm + bias) for this lane's quad.
// r15: tiered 8/4/2/1-wide edge batching. Mean degree = 10, so the old
// 8-wide + scalar-tail left ~35% of edges on a 1-outstanding-load serial chain;
// the 4/2 tiers batch those gathers. Accumulation stays ONE acc chain in strict
// ascending-edge order -> bit-identical results.
__device__ __forceinline__ float4 agg_body(const float* __restrict__ H,
                                           const int* __restrict__ offsets,
                                           const int* __restrict__ csr,
                                           const float* __restrict__ dis,
                                           const float* __restrict__ bias,
                                           int n, int qw){
  const float4* __restrict__ H4 = (const float4*)H;
  float dn = dis[n];
  int s = offsets[n], e = offsets[n + 1];
  float4 acc = make_float4(0.f, 0.f, 0.f, 0.f);
  int i = s;
  for (; i + 8 <= e; i += 8){
    int s0 = csr[i],   s1 = csr[i+1], s2 = csr[i+2], s3 = csr[i+3];
    int s4 = csr[i+4], s5 = csr[i+5], s6 = csr[i+6], s7 = csr[i+7];
    float4 h0 = H4[(size_t)s0 * 8 + qw];
    float4 h1 = H4[(size_t)s1 * 8 + qw];
    float4 h2 = H4[(size_t)s2 * 8 + qw];
    float4 h3 = H4[(size_t)s3 * 8 + qw];
    float4 h4 = H4[(size_t)s4 * 8 + qw];
    float4 h5 = H4[(size_t)s5 * 8 + qw];
    float4 h6 = H4[(size_t)s6 * 8 + qw];
    float4 h7 = H4[(size_t)s7 * 8 + qw];
    float w0 = __fmul_rn(dis[s0], dn), w1 = __fmul_rn(dis[s1], dn);
    float w2 = __fmul_rn(dis[s2], dn), w3 = __fmul_rn(dis[s3], dn);
    float w4 = __fmul_rn(dis[s4], dn), w5 = __fmul_rn(dis[s5], dn);
    float w6 = __fmul_rn(dis[s6], dn), w7 = __fmul_rn(dis[s7], dn);
    acc = acc_edge(acc, h0, w0);
    acc = acc_edge(acc, h1, w1);
    acc = acc_edge(acc, h2, w2);
    acc = acc_edge(acc, h3, w3);
    acc = acc_edge(acc, h4, w4);
    acc = acc_edge(acc, h5, w5);
    acc = acc_edge(acc, h6, w6);
    acc = acc_edge(acc, h7, w7);
  }
  if (i + 4 <= e){
    int s0 = csr[i], s1 = csr[i+1], s2 = csr[i+2], s3 = csr[i+3];
    float4 h0 = H4[(size_t)s0 * 8 + qw];
    float4 h1 = H4[(size_t)s1 * 8 + qw];
    float4 h2 = H4[(size_t)s2 * 8 + qw];
    float4 h3 = H4[(size_t)s3 * 8 + qw];
    float w0 = __fmul_rn(dis[s0], dn), w1 = __fmul_rn(dis[s1], dn);
    float w2 = __fmul_rn(dis[s2], dn), w3 = __fmul_rn(dis[s3], dn);
    acc = acc_edge(acc, h0, w0);
    acc = acc_edge(acc, h1, w1);
    acc = acc_edge(acc, h2, w2);
    acc = acc_edge(acc, h3, w3);
    i += 4;
  }
  if (i + 2 <= e){
    int s0 = csr[i], s1 = csr[i+1];
    float4 h0 = H4[(size_t)s0 * 8 + qw];
    float4 h1 = H4[(size_t)s1 * 8 + qw];
    float w0 = __fmul_rn(dis[s0], dn), w1 = __fmul_rn(dis[s1], dn);
    acc = acc_edge(acc, h0, w0);
    acc = acc_edge(acc, h1, w1);
    i += 2;
  }
  if (i < e){
    int sr = csr[i];
    float w = __fmul_rn(dis[sr], dn);
    acc = acc_edge(acc, H4[(size_t)sr * 8 + qw], w);
  }
  float4 hn = H4[(size_t)n * 8 + qw];
  float sw = __fmul_rn(dn, dn);
  float4 bb = ((const float4*)bias)[qw];
  float4 v;
  v.x = fmaxf(__fadd_rn(__fadd_rn(acc.x, __fmul_rn(hn.x, sw)), bb.x), 0.f);
  v.y = fmaxf(__fadd_rn(__fadd_rn(acc.y, __fmul_rn(hn.y, sw)), bb.y), 0.f);
  v.z = fmaxf(__fadd_rn(__fadd_rn(acc.z, __fmul_rn(hn.z, sw)), bb.z), 0.f);
  v.w = fmaxf(__fadd_rn(__fadd_rn(acc.w, __fmul_rn(hn.w, sw)), bb.w), 0.f);
  return v;
}

// final-layer agg: writes A (+ sort key)
__global__ __launch_bounds__(256) void agg_kernel(const float* __restrict__ H,
                           const int* __restrict__ offsets,
                           const int* __restrict__ csr, const float* __restrict__ dis,
                           const float* __restrict__ bias, float* __restrict__ A,
                           float* __restrict__ keyout, int N){
  int tid = blockIdx.x * 256 + threadIdx.x;
  int n = tid >> 3, qw = tid & 7;
  if (n >= N) return;
  float4 v = agg_body(H, offsets, csr, dis, bias, n, qw);
  ((float4*)A)[(size_t)n * 8 + qw] = v;
  if (keyout != nullptr && qw == 7) keyout[n] = v.w;
}

// fused agg + next-layer matmul (bit-identical to node_matmul<32>, k ascending)
__global__ __launch_bounds__(256) void agg_mm_kernel(const float* __restrict__ H,
                           const int* __restrict__ offsets,
                           const int* __restrict__ csr, const float* __restrict__ dis,
                           const float* __restrict__ bias,
                           const float* __restrict__ Wn,   // 32x32 row-major, L1-hot
                           float* __restrict__ H2, int N){
  int tid = blockIdx.x * 256 + threadIdx.x;
  int n = tid >> 3, qw = tid & 7;
  if (n >= N) return;   // whole 8-lane group exits together (node-aligned)
  float4 v = agg_body(H, offsets, csr, dis, bias, n, qw);

  const float4* __restrict__ Wn4 = (const float4*)Wn;  // Wn4[k*8 + col4]
  float4 o = make_float4(0.f, 0.f, 0.f, 0.f);
  #pragma unroll
  for (int p = 0; p < 8; p++){
    float4 hp;
    hp.x = __shfl(v.x, p, 8);
    hp.y = __shfl(v.y, p, 8);
    hp.z = __shfl(v.z, p, 8);
    hp.w = __shfl(v.w, p, 8);
    float4 wa = Wn4[(4 * p + 0) * 8 + qw];
    float4 wb = Wn4[(4 * p + 1) * 8 + qw];
    float4 wc = Wn4[(4 * p + 2) * 8 + qw];
    float4 wd = Wn4[(4 * p + 3) * 8 + qw];
    o.x = fmaf(hp.x, wa.x, o.x); o.y = fmaf(hp.x, wa.y, o.y);
    o.z = fmaf(hp.x, wa.z, o.z); o.w = fmaf(hp.x, wa.w, o.w);
    o.x = fmaf(hp.y, wb.x, o.x); o.y = fmaf(hp.y, wb.y, o.y);
    o.z = fmaf(hp.y, wb.z, o.z); o.w = fmaf(hp.y, wb.w, o.w);
    o.x = fmaf(hp.z, wc.x, o.x); o.y = fmaf(hp.z, wc.y, o.y);
    o.z = fmaf(hp.z, wc.z, o.z); o.w = fmaf(hp.z, wc.w, o.w);
    o.x = fmaf(hp.w, wd.x, o.x); o.y = fmaf(hp.w, wd.y, o.y);
    o.z = fmaf(hp.w, wd.z, o.z); o.w = fmaf(hp.w, wd.w, o.w);
  }
  ((float4*)H2)[(size_t)n * 8 + qw] = o;
}

// ---------------- graph boundaries (batch is sorted) ----------------
__global__ void gstarts_kernel(const int* __restrict__ batch, int* __restrict__ gstarts,
                               int N, int G){
  int g = blockIdx.x * blockDim.x + threadIdx.x;
  if (g > G) return;
  int lo = 0, hi = N;
  while (lo < hi){ int mid = (lo + hi) >> 1; if (batch[mid] < g) lo = mid + 1; else hi = mid; }
  gstarts[g] = lo;
}

// ------- fused head v5 (measured optimum of the graphs-per-wave family):
//   GPB=2 / 256-thread block, 128 threads = 2 waves per graph. ------
__global__ __launch_bounds__(256) void head_kernel(
    const float* __restrict__ A, const float* __restrict__ keys,
    const int* __restrict__ gstarts,
    const float* __restrict__ cw1, const float* __restrict__ cb1,
    const float* __restrict__ cw2, const float* __restrict__ cb2,
    const float* __restrict__ lw1, const float* __restrict__ lb1,
    const float* __restrict__ lw2, const float* __restrict__ lb2,
    float* __restrict__ out, int G){
  int t = threadIdx.x;
  int sub = t >> 7, lt = t & 127;    // waves 0-1 = graph 0, waves 2-3 = graph 1
  int g = blockIdx.x * GPB + sub;

  __shared__ float w1s[16 * 32 * 5];   // 2560, shared by both graphs
  __shared__ float w2s[32 * 16 * 5];   // 2560, shared by both graphs
  __shared__ float bufA[GPB][960];
  __shared__ float bufB[GPB][416];
  __shared__ int   sel[GPB][SORTK];

  for (int i = t; i < 2560; i += 256) w1s[i] = cw1[i];
  for (int i = t; i < 2560; i += 256) w2s[i] = cw2[i];
  for (int i = lt; i < 960; i += 128) bufA[sub][i] = 0.f;

  bool valid = (g < G);
  int s = 0, c = 0;
  if (valid){ s = gstarts[g]; c = gstarts[g + 1] - s; }
  bool fast = valid && (c <= KCAP);
  if (fast)
    for (int i = lt; i < c; i += 128) bufB[sub][i] = keys[s + i];   // coalesced
  __syncthreads();

  // stable top-30 rank: key desc, index asc (bit-identical selection)
  if (valid){
    if (fast){
      for (int i = lt; i < c; i += 128){
        float ki = bufB[sub][i];
        int rank = 0;
        #pragma unroll 8
        for (int j = 0; j < c; j++){
          float kj = bufB[sub][j];
          rank += (kj > ki || (kj == ki && j < i)) ? 1 : 0;
        }
        if (rank < SORTK) sel[sub][rank] = i;
      }
    } else {
      for (int i = lt; i < c; i += 128){
        float ki = keys[s + i];
        int rank = 0;
        for (int j = 0; j < c; j++){
          float kj = keys[s + j];
          if (kj > ki || (kj == ki && j < i)){
            if (++rank >= SORTK) break;
          }
        }
        if (rank < SORTK) sel[sub][rank] = i;
      }
    }
  }
  __syncthreads();

  // gather selected rows into conv layout sin_[ch*30+pos]
  if (valid){
    int kk = c < SORTK ? c : SORTK;
    for (int q = lt; q < kk * 32; q += 128){
      int pos = q >> 5, ch = q & 31;
      bufA[sub][ch * 30 + pos] = A[(size_t)(s + sel[sub][pos]) * 32 + ch];
    }
  }
  __syncthreads();

  // conv1: (32,30) -> (16,26)
  if (valid){
    for (int q = lt; q < 16 * 26; q += 128){
      int o = q / 26, tt = q - o * 26;
      float acc = cb1[o];
      const float* wo = &w1s[o * 160];
      #pragma unroll 4
      for (int i = 0; i < 32; i++){
        const float* si = &bufA[sub][i * 30 + tt];
        #pragma unroll
        for (int k = 0; k < 5; k++) acc = fmaf(si[k], wo[i * 5 + k], acc);
      }
      bufB[sub][q] = fmaxf(acc, 0.f);
    }
  }
  __syncthreads();

  // conv2: (16,26) -> (32,22)
  if (valid){
    for (int q = lt; q < 32 * 22; q += 128){
      int o = q / 22, tt = q - o * 22;
      float acc = cb2[o];
      const float* wo = &w2s[o * 80];
      #pragma unroll 4
      for (int i = 0; i < 16; i++){
        const float* si = &bufB[sub][i * 26 + tt];
        #pragma unroll
        for (int k = 0; k < 5; k++) acc = fmaf(si[k], wo[i * 5 + k], acc);
      }
      bufA[sub][q] = fmaxf(acc, 0.f);
    }
  }
  __syncthreads();

  // dense1: 704 -> 128; one thread per output, two accumulators preserving v4's
  // half-split FP order exactly: (lb1 + sum[0..351]) + (sum[352..703]), then relu.
  if (valid){
    int outi = lt;
    float accA = lb1[outi];
    float accB = 0.f;
    #pragma unroll 8
    for (int j = 0; j < 352; j++)
      accA = fmaf(bufA[sub][j], lw1[(size_t)j * 128 + outi], accA);
    #pragma unroll 8
    for (int j = 352; j < 704; j++)
      accB = fmaf(bufA[sub][j], lw1[(size_t)j * 128 + outi], accB);
    bufB[sub][outi] = fmaxf(accA + accB, 0.f);
  }
  __syncthreads();

  // dense2: 128 -> 1, one-wave shuffle reduce (lt<64 is a full wave in each sub)
  if (valid && lt < 64){
    float v = __fadd_rn(__fmul_rn(bufB[sub][lt], lw2[lt]),
                        __fmul_rn(bufB[sub][lt + 64], lw2[lt + 64]));
    #pragma unroll
    for (int o = 32; o > 0; o >>= 1) v += __shfl_xor(v, o, 64);
    if (lt == 0) out[g] = v + lb2[0];
  }
}

// ---------------- launch ----------------
extern "C" void kernel_launch(void* const* d_in, const int* in_sizes, int n_in,
                              void* d_out, int out_size, void* d_ws, size_t ws_size,
                              hipStream_t stream){
  const float* x     = (const float*)d_in[0];
  const int*   ei    = (const int*)  d_in[1];
  const int*   batch = (const int*)  d_in[2];
  const float* W1  = (const float*)d_in[4];
  const float* b1  = (const float*)d_in[5];
  const float* W2  = (const float*)d_in[6];
  const float* b2  = (const float*)d_in[7];
  const float* W3  = (const float*)d_in[8];
  const float* b3  = (const float*)d_in[9];
  const float* cw1 = (const float*)d_in[10];
  const float* cb1 = (const float*)d_in[11];
  const float* cw2 = (const float*)d_in[12];
  const float* cb2 = (const float*)d_in[13];
  const float* lw1 = (const float*)d_in[14];
  const float* lb1 = (const float*)d_in[15];
  const float* lw2 = (const float*)d_in[16];
  const float* lb2 = (const float*)d_in[17];

  int N = in_sizes[0] / 9;
  int E = in_sizes[1] / 2;
  int G = out_size;
  const int* srcs = ei;
  const int* dsts = ei + E;
  int NB = ceil_div_i(N, BNODES);
  int segsz = ceil_div_i(E, NSEG);

  char* base = (char*)d_ws;
  size_t off = 0;
  auto alloc = [&](size_t bytes) -> void* {
    off = (off + 255) & ~(size_t)255;
    void* r = base + off; off += bytes; return r;
  };
  float* dis    = (float*)alloc((size_t)N * 4);
  float* H      = (float*)alloc((size_t)N * 32 * 4);   // aliased as staging
  float* A      = (float*)alloc((size_t)N * 32 * 4);
  float* keyarr = (float*)alloc((size_t)N * 4);
  int*   offs   = (int*)alloc((size_t)(N + 1) * 4);
  int*   csr    = (int*)alloc((size_t)E * 4);
  int*   gst    = (int*)alloc((size_t)(G + 1) * 4);
  int*   hist   = (int*)alloc((size_t)NSEG * NB * 4);
  int*   segoff = (int*)alloc((size_t)NSEG * NB * 4);
  int*   btot   = (int*)alloc((size_t)NB * 4);
  int*   bbase  = (int*)alloc((size_t)(NB + 1) * 4);
  unsigned* staging = (unsigned*)H;
  (void)ws_size; (void)n_in;

  hist_kernel<<<NSEG, 1024, 0, stream>>>(dsts, hist, E, NB, segsz);
  segscanA<<<ceil_div_i(NB * 64, 256), 256, 0, stream>>>(hist, segoff, btot, NB, NSEG);
  segscanB<<<1, 1024, 0, stream>>>(btot, bbase, NB);
  scatter_kernel<<<NSEG, 1024, 0, stream>>>(dsts, segoff, bbase, staging, E, NB, segsz);
  bucket_sort_kernel<<<NB, 256, 0, stream>>>(bbase, staging, srcs, csr, offs, dis, N, NB, E);

  int ntm = ceil_div_i((long long)N * 32, 256);
  int nta = ceil_div_i((long long)N * 8, 256);
  // layer 1: H = x@W1 ; layer1 agg fused with matmul of W2 -> A holds next H
  node_matmul<9><<<ntm, 256, 0, stream>>>(x, W1, H, N);
  agg_mm_kernel<<<nta, 256, 0, stream>>>(H, offs, csr, dis, b1, W2, A, N);
  // layer 2: agg fused with matmul of W3 -> H holds next H
  agg_mm_kernel<<<nta, 256, 0, stream>>>(A, offs, csr, dis, b2, W3, H, N);
  // layer 3: plain agg -> A (+ sort keys) for the head
  agg_kernel<<<nta, 256, 0, stream>>>(H, offs, csr, dis, b3, A, keyarr, N);

  gstarts_kernel<<<ceil_div_i(G + 1, 256), 256, 0, stream>>>(batch, gst, N, G);
  head_kernel<<<ceil_div_i(G, GPB), 256, 0, stream>>>(A, keyarr, gst, cw1, cb1, cw2, cb2,
                                                      lw1, lb1, lw2, lb2, (float*)d_out, G);
}

// Round 16
// 462.587 us; speedup vs baseline: 1.1060x; 1.0043x over previous
//
#include <hip/hip_runtime.h>

typedef unsigned long long ull;

#define HIDDEN 32
#define SORTK 30
#define KCAP 256              // max nodes/graph fast path (mean 122, sd 11; 12 sigma)
#define GPB 2                 // graphs per block (shared weight stage)
#define BSH 7                 // 128 nodes per bucket
#define BNODES (1 << BSH)
#define BCAP 1536
#define HMAX 2048
#define NSEG 256
#define EID_BITS 22           // E = 2.5M < 4.19M
#define EID_MASK ((1u << EID_BITS) - 1)

static inline int ceil_div_i(long long a, int b){ return (int)((a + b - 1) / b); }

// ---------------- phase 1: per-segment LDS histogram ----------------
__global__ __launch_bounds__(1024) void hist_kernel(const int* __restrict__ dsts,
                                                    int* __restrict__ hist,
                                                    int E, int NB, int segsz){
  __shared__ int h[HMAX];
  for (int i = threadIdx.x; i < NB; i += 1024) h[i] = 0;
  __syncthreads();
  int seg = blockIdx.x;
  int e0 = seg * segsz;
  int e1 = e0 + segsz; if (e1 > E) e1 = E;
  for (int e = e0 + threadIdx.x; e < e1; e += 1024)
    atomicAdd(&h[dsts[e] >> BSH], 1);
  __syncthreads();
  for (int i = threadIdx.x; i < NB; i += 1024) hist[seg * NB + i] = h[i];
}

// ---------------- phase 2a: per-bucket prefix over segments (1 wave / bucket) -------
__global__ __launch_bounds__(256) void segscanA(const int* __restrict__ hist,
                                                int* __restrict__ segoff,
                                                int* __restrict__ btot,
                                                int NB, int S){
  int wv = (blockIdx.x * 256 + threadIdx.x) >> 6;
  int lane = threadIdx.x & 63;
  if (wv >= NB) return;
  int b = wv;
  int run_base = 0;
  for (int chunk = 0; chunk < S; chunk += 64){
    int s = chunk + lane;
    int v = (s < S) ? hist[(size_t)s * NB + b] : 0;
    int x = v;
    #pragma unroll
    for (int o = 1; o < 64; o <<= 1){ int y = __shfl_up(x, o, 64); if (lane >= o) x += y; }
    if (s < S) segoff[(size_t)s * NB + b] = run_base + x - v;
    run_base += __shfl(x, 63, 64);
  }
  if (lane == 0) btot[b] = run_base;
}

// ---------------- phase 2b: exclusive scan of bucket totals (1 block) ----------------
__global__ __launch_bounds__(1024) void segscanB(const int* __restrict__ btot,
                                                 int* __restrict__ bbase, int NB){
  int t = threadIdx.x;
  int b0 = t * 2, b1 = t * 2 + 1;
  int v0 = (b0 < NB) ? btot[b0] : 0;
  int v1 = (b1 < NB) ? btot[b1] : 0;
  int pair = v0 + v1;
  int lane = t & 63, wid = t >> 6;
  int x = pair;
  for (int o = 1; o < 64; o <<= 1){ int y = __shfl_up(x, o, 64); if (lane >= o) x += y; }
  __shared__ int wsum[16]; __shared__ int woff[16];
  if (lane == 63) wsum[wid] = x;
  __syncthreads();
  if (t == 0){ int run = 0; for (int w = 0; w < 16; w++){ woff[w] = run; run += wsum[w]; } }
  __syncthreads();
  int excl = x - pair + woff[wid];
  if (b0 < NB) bbase[b0] = excl;
  if (b1 < NB) bbase[b1] = excl + v0;
}

// ---------------- phase 3: scatter 32-bit key (ld,eid), block-private regions ------
__global__ __launch_bounds__(1024) void scatter_kernel(const int* __restrict__ dsts,
                                                       const int* __restrict__ segoff,
                                                       const int* __restrict__ bbase,
                                                       unsigned* __restrict__ staging,
                                                       int E, int NB, int segsz){
  __shared__ int cur[HMAX];
  int seg = blockIdx.x;
  for (int i = threadIdx.x; i < NB; i += 1024) cur[i] = segoff[(size_t)seg * NB + i] + bbase[i];
  __syncthreads();
  int e0 = seg * segsz;
  int e1 = e0 + segsz; if (e1 > E) e1 = E;
  for (int e = e0 + threadIdx.x; e < e1; e += 1024){
    int d = dsts[e];
    int slot = atomicAdd(&cur[d >> BSH], 1);
    staging[slot] = ((unsigned)(d & (BNODES - 1)) << EID_BITS) | (unsigned)e;
  }
}

// ---------------- phase 4: per-bucket LDS bin + parallel rank -> CSR ----------------
__global__ __launch_bounds__(256) void bucket_sort_kernel(
    const int* __restrict__ bbase, const unsigned* __restrict__ staging,
    const int* __restrict__ srcs,
    int* __restrict__ csr, int* __restrict__ offs,
    float* __restrict__ dis, int N, int NB, int E){
  __shared__ unsigned ebuf[BCAP];
  __shared__ unsigned obuf[BCAP];
  __shared__ int cnt[BNODES];
  __shared__ int cur[BNODES];
  __shared__ int base0[BNODES];
  __shared__ int w0tot;
  int b = blockIdx.x, t = threadIdx.x;
  int n0 = b << BSH;
  int n1 = n0 + BNODES; if (n1 > N) n1 = N;
  int gbeg = bbase[b];
  int gend = (b + 1 < NB) ? bbase[b + 1] : E;
  int cnt_all = gend - gbeg;
  if (t < BNODES) cnt[t] = 0;
  __syncthreads();

  if (cnt_all <= BCAP){
    for (int i = t; i < cnt_all; i += 256){
      unsigned k = staging[gbeg + i];
      ebuf[i] = k;
      atomicAdd(&cnt[k >> EID_BITS], 1);
    }
    __syncthreads();
    int v = 0, x = 0;
    if (t < BNODES){
      v = cnt[t];
      int lane = t & 63, wid = t >> 6;
      x = v;
      for (int o = 1; o < 64; o <<= 1){ int y = __shfl_up(x, o, 64); if (lane >= o) x += y; }
      if (wid == 0 && lane == 63) w0tot = x;
    }
    __syncthreads();   // uniform: makes w0tot visible to wave 1
    if (t < BNODES){
      int wid = t >> 6;
      int ls = x - v + (wid ? w0tot : 0);
      cur[t] = ls;
      base0[t] = ls;
      int n = n0 + t;
      if (n < n1){
        float dd = (float)v + 1.0f;
        dis[n]  = __fdiv_rn(1.0f, __fsqrt_rn(dd));
        offs[n] = gbeg + ls;
      }
    }
    __syncthreads();
    for (int i = t; i < cnt_all; i += 256){
      unsigned k = ebuf[i];
      int pos = atomicAdd(&cur[k >> EID_BITS], 1);
      obuf[pos] = k;
    }
    __syncthreads();
    for (int i = t; i < cnt_all; i += 256){
      unsigned k = obuf[i];
      int nd = (int)(k >> EID_BITS);
      int base = base0[nd];
      int vn = cnt[nd];
      int r = 0;
      for (int j = 0; j < vn; j++) r += (obuf[base + j] < k) ? 1 : 0;
      csr[gbeg + base + r] = srcs[k & EID_MASK];
    }
  } else {
    // statistically unreachable fallback (correct, slow)
    if (t < BNODES){
      int n = n0 + t;
      int deg = 0;
      if (n < n1){
        for (int i = gbeg; i < gend; i++) if ((int)(staging[i] >> EID_BITS) == t) deg++;
        float dd = (float)deg + 1.0f;
        dis[n] = __fdiv_rn(1.0f, __fsqrt_rn(dd));
      }
      cnt[t] = (n < n1) ? deg : 0;
    }
    __syncthreads();
    if (t < BNODES){
      int n = n0 + t;
      if (n < n1){
        int deg = cnt[t];
        int ls = gbeg; for (int q = 0; q < t; q++) ls += cnt[q];
        offs[n] = ls;
        unsigned prev = 0;
        for (int o = 0; o < deg; o++){
          unsigned best = 0xFFFFFFFFu;
          for (int i = gbeg; i < gend; i++){
            unsigned k = staging[i];
            if ((int)(k >> EID_BITS) == t && (o == 0 || k > prev) && k < best) best = k;
          }
          csr[ls + o] = srcs[best & EID_MASK]; prev = best;
        }
      }
    }
  }
  if (b == 0 && t == 0) offs[N] = E;
}

// ---------------- per-node matmul h = x @ W ----------------
template<int K>
__global__ void node_matmul(const float* __restrict__ xin, const float* __restrict__ W,
                            float* __restrict__ H, int N){
  __shared__ float Ws[K * 32];
  for (int i = threadIdx.x; i < K * 32; i += blockDim.x) Ws[i] = W[i];
  __syncthreads();
  int tid = blockIdx.x * blockDim.x + threadIdx.x;
  int n = tid >> 5, c = tid & 31;
  if (n >= N) return;
  const float* xr = xin + (size_t)n * K;
  float acc = 0.f;
  #pragma unroll
  for (int k = 0; k < K; k++) acc = fmaf(xr[k], Ws[k * 32 + c], acc);
  H[(size_t)n * 32 + c] = acc;
}

// ---------------- GCN aggregation helpers ----------------
__device__ __forceinline__ float4 acc_edge(float4 a, float4 h, float w){
  a.x = __fadd_rn(a.x, __fmul_rn(h.x, w));
  a.y = __fadd_rn(a.y, __fmul_rn(h.y, w));
  a.z = __fadd_rn(a.z, __fmul_rn(h.z, w));
  a.w = __fadd_rn(a.w, __fmul_rn(h.w, w));
  return a;
}

// core agg body: returns v = relu(agg + selfterm + bias) for this lane's quad.
// r16: issue-all-then-accumulate tail. After the (rare, deg>=16) 8-wide main loop,
// rem < 16 decomposes in binary as 8*h8 + 4*h4 + 2*h2 + h1 -- exactly r15's tier
// order. All tier LOADS are issued first (up to 15 outstanding gathers), then the
// FMA chains run in the same 8,4,2,1 edge order -> bit-identical results with ~2x
// deeper memory-level parallelism for the typical deg~10 node.
__device__ __forceinline__ float4 agg_body(const float* __restrict__ H,
                                           const int* __restrict__ offsets,
                                           const int* __restrict__ csr,
                                           const float* __restrict__ dis,
                                           const float* __restrict__ bias,
                                           int n, int qw){
  const float4* __restrict__ H4 = (const float4*)H;
  float dn = dis[n];
  int s = offsets[n], e = offsets[n + 1];
  float4 acc = make_float4(0.f, 0.f, 0.f, 0.f);
  int i = s;
  // main loop: only while >=16 remain (deg>=16 is ~5% of nodes)
  for (; i + 16 <= e; i += 8){
    int s0 = csr[i],   s1 = csr[i+1], s2 = csr[i+2], s3 = csr[i+3];
    int s4 = csr[i+4], s5 = csr[i+5], s6 = csr[i+6], s7 = csr[i+7];
    float4 h0 = H4[(size_t)s0 * 8 + qw];
    float4 h1 = H4[(size_t)s1 * 8 + qw];
    float4 h2 = H4[(size_t)s2 * 8 + qw];
    float4 h3 = H4[(size_t)s3 * 8 + qw];
    float4 h4 = H4[(size_t)s4 * 8 + qw];
    float4 h5 = H4[(size_t)s5 * 8 + qw];
    float4 h6 = H4[(size_t)s6 * 8 + qw];
    float4 h7 = H4[(size_t)s7 * 8 + qw];
    float w0 = __fmul_rn(dis[s0], dn), w1 = __fmul_rn(dis[s1], dn);
    float w2 = __fmul_rn(dis[s2], dn), w3 = __fmul_rn(dis[s3], dn);
    float w4 = __fmul_rn(dis[s4], dn), w5 = __fmul_rn(dis[s5], dn);
    float w6 = __fmul_rn(dis[s6], dn), w7 = __fmul_rn(dis[s7], dn);
    acc = acc_edge(acc, h0, w0);
    acc = acc_edge(acc, h1, w1);
    acc = acc_edge(acc, h2, w2);
    acc = acc_edge(acc, h3, w3);
    acc = acc_edge(acc, h4, w4);
    acc = acc_edge(acc, h5, w5);
    acc = acc_edge(acc, h6, w6);
    acc = acc_edge(acc, h7, w7);
  }
  // tail: rem in [0,15], binary decomposition 8/4/2/1 (same edge order as r15)
  int rem = e - i;
  bool h8 = (rem & 8) != 0;
  int p4 = i + (h8 ? 8 : 0);
  bool h4t = (rem & 4) != 0;
  int p2 = p4 + (h4t ? 4 : 0);
  bool h2t = (rem & 2) != 0;
  int p1 = p2 + (h2t ? 2 : 0);
  bool h1t = (rem & 1) != 0;

  float4 a0, a1, a2, a3, a4, a5, a6, a7;
  float  wa0, wa1, wa2, wa3, wa4, wa5, wa6, wa7;
  float4 b0, b1, b2, b3;
  float  wb0, wb1, wb2, wb3;
  float4 c0, c1;
  float  wc0, wc1;
  float4 d0;
  float  wd0;

  // issue ALL tail loads first
  if (h8){
    int s0 = csr[i],   s1 = csr[i+1], s2 = csr[i+2], s3 = csr[i+3];
    int s4 = csr[i+4], s5 = csr[i+5], s6 = csr[i+6], s7 = csr[i+7];
    a0 = H4[(size_t)s0 * 8 + qw]; a1 = H4[(size_t)s1 * 8 + qw];
    a2 = H4[(size_t)s2 * 8 + qw]; a3 = H4[(size_t)s3 * 8 + qw];
    a4 = H4[(size_t)s4 * 8 + qw]; a5 = H4[(size_t)s5 * 8 + qw];
    a6 = H4[(size_t)s6 * 8 + qw]; a7 = H4[(size_t)s7 * 8 + qw];
    wa0 = __fmul_rn(dis[s0], dn); wa1 = __fmul_rn(dis[s1], dn);
    wa2 = __fmul_rn(dis[s2], dn); wa3 = __fmul_rn(dis[s3], dn);
    wa4 = __fmul_rn(dis[s4], dn); wa5 = __fmul_rn(dis[s5], dn);
    wa6 = __fmul_rn(dis[s6], dn); wa7 = __fmul_rn(dis[s7], dn);
  }
  if (h4t){
    int s0 = csr[p4], s1 = csr[p4+1], s2 = csr[p4+2], s3 = csr[p4+3];
    b0 = H4[(size_t)s0 * 8 + qw]; b1 = H4[(size_t)s1 * 8 + qw];
    b2 = H4[(size_t)s2 * 8 + qw]; b3 = H4[(size_t)s3 * 8 + qw];
    wb0 = __fmul_rn(dis[s0], dn); wb1 = __fmul_rn(dis[s1], dn);
    wb2 = __fmul_rn(dis[s2], dn); wb3 = __fmul_rn(dis[s3], dn);
  }
  if (h2t){
    int s0 = csr[p2], s1 = csr[p2+1];
    c0 = H4[(size_t)s0 * 8 + qw]; c1 = H4[(size_t)s1 * 8 + qw];
    wc0 = __fmul_rn(dis[s0], dn); wc1 = __fmul_rn(dis[s1], dn);
  }
  if (h1t){
    int s0 = csr[p1];
    d0 = H4[(size_t)s0 * 8 + qw];
    wd0 = __fmul_rn(dis[s0], dn);
  }
  // accumulate in the exact 8,4,2,1 edge order
  if (h8){
    acc = acc_edge(acc, a0, wa0);
    acc = acc_edge(acc, a1, wa1);
    acc = acc_edge(acc, a2, wa2);
    acc = acc_edge(acc, a3, wa3);
    acc = acc_edge(acc, a4, wa4);
    acc = acc_edge(acc, a5, wa5);
    acc = acc_edge(acc, a6, wa6);
    acc = acc_edge(acc, a7, wa7);
  }
  if (h4t){
    acc = acc_edge(acc, b0, wb0);
    acc = acc_edge(acc, b1, wb1);
    acc = acc_edge(acc, b2, wb2);
    acc = acc_edge(acc, b3, wb3);
  }
  if (h2t){
    acc = acc_edge(acc, c0, wc0);
    acc = acc_edge(acc, c1, wc1);
  }
  if (h1t){
    acc = acc_edge(acc, d0, wd0);
  }

  float4 hn = H4[(size_t)n * 8 + qw];
  float sw = __fmul_rn(dn, dn);
  float4 bb = ((const float4*)bias)[qw];
  float4 v;
  v.x = fmaxf(__fadd_rn(__fadd_rn(acc.x, __fmul_rn(hn.x, sw)), bb.x), 0.f);
  v.y = fmaxf(__fadd_rn(__fadd_rn(acc.y, __fmul_rn(hn.y, sw)), bb.y), 0.f);
  v.z = fmaxf(__fadd_rn(__fadd_rn(acc.z, __fmul_rn(hn.z, sw)), bb.z), 0.f);
  v.w = fmaxf(__fadd_rn(__fadd_rn(acc.w, __fmul_rn(hn.w, sw)), bb.w), 0.f);
  return v;
}

// final-layer agg: writes A (+ sort key)
__global__ __launch_bounds__(256) void agg_kernel(const float* __restrict__ H,
                           const int* __restrict__ offsets,
                           const int* __restrict__ csr, const float* __restrict__ dis,
                           const float* __restrict__ bias, float* __restrict__ A,
                           float* __restrict__ keyout, int N){
  int tid = blockIdx.x * 256 + threadIdx.x;
  int n = tid >> 3, qw = tid & 7;
  if (n >= N) return;
  float4 v = agg_body(H, offsets, csr, dis, bias, n, qw);
  ((float4*)A)[(size_t)n * 8 + qw] = v;
  if (keyout != nullptr && qw == 7) keyout[n] = v.w;
}

// fused agg + next-layer matmul (bit-identical to node_matmul<32>, k ascending)
__global__ __launch_bounds__(256) void agg_mm_kernel(const float* __restrict__ H,
                           const int* __restrict__ offsets,
                           const int* __restrict__ csr, const float* __restrict__ dis,
                           const float* __restrict__ bias,
                           const float* __restrict__ Wn,   // 32x32 row-major, L1-hot
                           float* __restrict__ H2, int N){
  int tid = blockIdx.x * 256 + threadIdx.x;
  int n = tid >> 3, qw = tid & 7;
  if (n >= N) return;   // whole 8-lane group exits together (node-aligned)
  float4 v = agg_body(H, offsets, csr, dis, bias, n, qw);

  const float4* __restrict__ Wn4 = (const float4*)Wn;  // Wn4[k*8 + col4]
  float4 o = make_float4(0.f, 0.f, 0.f, 0.f);
  #pragma unroll
  for (int p = 0; p < 8; p++){
    float4 hp;
    hp.x = __shfl(v.x, p, 8);
    hp.y = __shfl(v.y, p, 8);
    hp.z = __shfl(v.z, p, 8);
    hp.w = __shfl(v.w, p, 8);
    float4 wa = Wn4[(4 * p + 0) * 8 + qw];
    float4 wb = Wn4[(4 * p + 1) * 8 + qw];
    float4 wc = Wn4[(4 * p + 2) * 8 + qw];
    float4 wd = Wn4[(4 * p + 3) * 8 + qw];
    o.x = fmaf(hp.x, wa.x, o.x); o.y = fmaf(hp.x, wa.y, o.y);
    o.z = fmaf(hp.x, wa.z, o.z); o.w = fmaf(hp.x, wa.w, o.w);
    o.x = fmaf(hp.y, wb.x, o.x); o.y = fmaf(hp.y, wb.y, o.y);
    o.z = fmaf(hp.y, wb.z, o.z); o.w = fmaf(hp.y, wb.w, o.w);
    o.x = fmaf(hp.z, wc.x, o.x); o.y = fmaf(hp.z, wc.y, o.y);
    o.z = fmaf(hp.z, wc.z, o.z); o.w = fmaf(hp.z, wc.w, o.w);
    o.x = fmaf(hp.w, wd.x, o.x); o.y = fmaf(hp.w, wd.y, o.y);
    o.z = fmaf(hp.w, wd.z, o.z); o.w = fmaf(hp.w, wd.w, o.w);
  }
  ((float4*)H2)[(size_t)n * 8 + qw] = o;
}

// ---------------- graph boundaries (batch is sorted) ----------------
__global__ void gstarts_kernel(const int* __restrict__ batch, int* __restrict__ gstarts,
                               int N, int G){
  int g = blockIdx.x * blockDim.x + threadIdx.x;
  if (g > G) return;
  int lo = 0, hi = N;
  while (lo < hi){ int mid = (lo + hi) >> 1; if (batch[mid] < g) lo = mid + 1; else hi = mid; }
  gstarts[g] = lo;
}

// ------- fused head v5 (measured optimum of the graphs-per-wave family):
//   GPB=2 / 256-thread block, 128 threads = 2 waves per graph. ------
__global__ __launch_bounds__(256) void head_kernel(
    const float* __restrict__ A, const float* __restrict__ keys,
    const int* __restrict__ gstarts,
    const float* __restrict__ cw1, const float* __restrict__ cb1,
    const float* __restrict__ cw2, const float* __restrict__ cb2,
    const float* __restrict__ lw1, const float* __restrict__ lb1,
    const float* __restrict__ lw2, const float* __restrict__ lb2,
    float* __restrict__ out, int G){
  int t = threadIdx.x;
  int sub = t >> 7, lt = t & 127;    // waves 0-1 = graph 0, waves 2-3 = graph 1
  int g = blockIdx.x * GPB + sub;

  __shared__ float w1s[16 * 32 * 5];   // 2560, shared by both graphs
  __shared__ float w2s[32 * 16 * 5];   // 2560, shared by both graphs
  __shared__ float bufA[GPB][960];
  __shared__ float bufB[GPB][416];
  __shared__ int   sel[GPB][SORTK];

  for (int i = t; i < 2560; i += 256) w1s[i] = cw1[i];
  for (int i = t; i < 2560; i += 256) w2s[i] = cw2[i];
  for (int i = lt; i < 960; i += 128) bufA[sub][i] = 0.f;

  bool valid = (g < G);
  int s = 0, c = 0;
  if (valid){ s = gstarts[g]; c = gstarts[g + 1] - s; }
  bool fast = valid && (c <= KCAP);
  if (fast)
    for (int i = lt; i < c; i += 128) bufB[sub][i] = keys[s + i];   // coalesced
  __syncthreads();

  // stable top-30 rank: key desc, index asc (bit-identical selection)
  if (valid){
    if (fast){
      for (int i = lt; i < c; i += 128){
        float ki = bufB[sub][i];
        int rank = 0;
        #pragma unroll 8
        for (int j = 0; j < c; j++){
          float kj = bufB[sub][j];
          rank += (kj > ki || (kj == ki && j < i)) ? 1 : 0;
        }
        if (rank < SORTK) sel[sub][rank] = i;
      }
    } else {
      for (int i = lt; i < c; i += 128){
        float ki = keys[s + i];
        int rank = 0;
        for (int j = 0; j < c; j++){
          float kj = keys[s + j];
          if (kj > ki || (kj == ki && j < i)){
            if (++rank >= SORTK) break;
          }
        }
        if (rank < SORTK) sel[sub][rank] = i;
      }
    }
  }
  __syncthreads();

  // gather selected rows into conv layout sin_[ch*30+pos]
  if (valid){
    int kk = c < SORTK ? c : SORTK;
    for (int q = lt; q < kk * 32; q += 128){
      int pos = q >> 5, ch = q & 31;
      bufA[sub][ch * 30 + pos] = A[(size_t)(s + sel[sub][pos]) * 32 + ch];
    }
  }
  __syncthreads();

  // conv1: (32,30) -> (16,26)
  if (valid){
    for (int q = lt; q < 16 * 26; q += 128){
      int o = q / 26, tt = q - o * 26;
      float acc = cb1[o];
      const float* wo = &w1s[o * 160];
      #pragma unroll 4
      for (int i = 0; i < 32; i++){
        const float* si = &bufA[sub][i * 30 + tt];
        #pragma unroll
        for (int k = 0; k < 5; k++) acc = fmaf(si[k], wo[i * 5 + k], acc);
      }
      bufB[sub][q] = fmaxf(acc, 0.f);
    }
  }
  __syncthreads();

  // conv2: (16,26) -> (32,22)
  if (valid){
    for (int q = lt; q < 32 * 22; q += 128){
      int o = q / 22, tt = q - o * 22;
      float acc = cb2[o];
      const float* wo = &w2s[o * 80];
      #pragma unroll 4
      for (int i = 0; i < 16; i++){
        const float* si = &bufB[sub][i * 26 + tt];
        #pragma unroll
        for (int k = 0; k < 5; k++) acc = fmaf(si[k], wo[i * 5 + k], acc);
      }
      bufA[sub][q] = fmaxf(acc, 0.f);
    }
  }
  __syncthreads();

  // dense1: 704 -> 128; one thread per output, two accumulators preserving v4's
  // half-split FP order exactly: (lb1 + sum[0..351]) + (sum[352..703]), then relu.
  if (valid){
    int outi = lt;
    float accA = lb1[outi];
    float accB = 0.f;
    #pragma unroll 8
    for (int j = 0; j < 352; j++)
      accA = fmaf(bufA[sub][j], lw1[(size_t)j * 128 + outi], accA);
    #pragma unroll 8
    for (int j = 352; j < 704; j++)
      accB = fmaf(bufA[sub][j], lw1[(size_t)j * 128 + outi], accB);
    bufB[sub][outi] = fmaxf(accA + accB, 0.f);
  }
  __syncthreads();

  // dense2: 128 -> 1, one-wave shuffle reduce (lt<64 is a full wave in each sub)
  if (valid && lt < 64){
    float v = __fadd_rn(__fmul_rn(bufB[sub][lt], lw2[lt]),
                        __fmul_rn(bufB[sub][lt + 64], lw2[lt + 64]));
    #pragma unroll
    for (int o = 32; o > 0; o >>= 1) v += __shfl_xor(v, o, 64);
    if (lt == 0) out[g] = v + lb2[0];
  }
}

// ---------------- launch ----------------
extern "C" void kernel_launch(void* const* d_in, const int* in_sizes, int n_in,
                              void* d_out, int out_size, void* d_ws, size_t ws_size,
                              hipStream_t stream){
  const float* x     = (const float*)d_in[0];
  const int*   ei    = (const int*)  d_in[1];
  const int*   batch = (const int*)  d_in[2];
  const float* W1  = (const float*)d_in[4];
  const float* b1  = (const float*)d_in[5];
  const float* W2  = (const float*)d_in[6];
  const float* b2  = (const float*)d_in[7];
  const float* W3  = (const float*)d_in[8];
  const float* b3  = (const float*)d_in[9];
  const float* cw1 = (const float*)d_in[10];
  const float* cb1 = (const float*)d_in[11];
  const float* cw2 = (const float*)d_in[12];
  const float* cb2 = (const float*)d_in[13];
  const float* lw1 = (const float*)d_in[14];
  const float* lb1 = (const float*)d_in[15];
  const float* lw2 = (const float*)d_in[16];
  const float* lb2 = (const float*)d_in[17];

  int N = in_sizes[0] / 9;
  int E = in_sizes[1] / 2;
  int G = out_size;
  const int* srcs = ei;
  const int* dsts = ei + E;
  int NB = ceil_div_i(N, BNODES);
  int segsz = ceil_div_i(E, NSEG);

  char* base = (char*)d_ws;
  size_t off = 0;
  auto alloc = [&](size_t bytes) -> void* {
    off = (off + 255) & ~(size_t)255;
    void* r = base + off; off += bytes; return r;
  };
  float* dis    = (float*)alloc((size_t)N * 4);
  float* H      = (float*)alloc((size_t)N * 32 * 4);   // aliased as staging
  float* A      = (float*)alloc((size_t)N * 32 * 4);
  float* keyarr = (float*)alloc((size_t)N * 4);
  int*   offs   = (int*)alloc((size_t)(N + 1) * 4);
  int*   csr    = (int*)alloc((size_t)E * 4);
  int*   gst    = (int*)alloc((size_t)(G + 1) * 4);
  int*   hist   = (int*)alloc((size_t)NSEG * NB * 4);
  int*   segoff = (int*)alloc((size_t)NSEG * NB * 4);
  int*   btot   = (int*)alloc((size_t)NB * 4);
  int*   bbase  = (int*)alloc((size_t)(NB + 1) * 4);
  unsigned* staging = (unsigned*)H;
  (void)ws_size; (void)n_in;

  hist_kernel<<<NSEG, 1024, 0, stream>>>(dsts, hist, E, NB, segsz);
  segscanA<<<ceil_div_i(NB * 64, 256), 256, 0, stream>>>(hist, segoff, btot, NB, NSEG);
  segscanB<<<1, 1024, 0, stream>>>(btot, bbase, NB);
  scatter_kernel<<<NSEG, 1024, 0, stream>>>(dsts, segoff, bbase, staging, E, NB, segsz);
  bucket_sort_kernel<<<NB, 256, 0, stream>>>(bbase, staging, srcs, csr, offs, dis, N, NB, E);

  int ntm = ceil_div_i((long long)N * 32, 256);
  int nta = ceil_div_i((long long)N * 8, 256);
  // layer 1: H = x@W1 ; layer1 agg fused with matmul of W2 -> A holds next H
  node_matmul<9><<<ntm, 256, 0, stream>>>(x, W1, H, N);
  agg_mm_kernel<<<nta, 256, 0, stream>>>(H, offs, csr, dis, b1, W2, A, N);
  // layer 2: agg fused with matmul of W3 -> H holds next H
  agg_mm_kernel<<<nta, 256, 0, stream>>>(A, offs, csr, dis, b2, W3, H, N);
  // layer 3: plain agg -> A (+ sort keys) for the head
  agg_kernel<<<nta, 256, 0, stream>>>(H, offs, csr, dis, b3, A, keyarr, N);

  gstarts_kernel<<<ceil_div_i(G + 1, 256), 256, 0, stream>>>(batch, gst, N, G);
  head_kernel<<<ceil_div_i(G, GPB), 256, 0, stream>>>(A, keyarr, gst, cw1, cb1, cw2, cb2,
                                                      lw1, lb1, lw2, lb2, (float*)d_out, G);
}

// Round 17
// 457.876 us; speedup vs baseline: 1.1174x; 1.0103x over previous
//
#include <hip/hip_runtime.h>

typedef unsigned long long ull;

#define HIDDEN 32
#define SORTK 30
#define KCAP 256              // max nodes/graph fast path (mean 122, sd 11; 12 sigma)
#define GPB 2                 // graphs per block (shared weight stage)
#define BSH 7                 // 128 nodes per bucket
#define BNODES (1 << BSH)
#define BCAP 1536
#define HMAX 2048
#define NSEG 256
#define EID_BITS 22           // E = 2.5M < 4.19M
#define EID_MASK ((1u << EID_BITS) - 1)

static inline int ceil_div_i(long long a, int b){ return (int)((a + b - 1) / b); }

// ---------------- phase 1: per-segment LDS histogram ----------------
__global__ __launch_bounds__(1024) void hist_kernel(const int* __restrict__ dsts,
                                                    int* __restrict__ hist,
                                                    int E, int NB, int segsz){
  __shared__ int h[HMAX];
  for (int i = threadIdx.x; i < NB; i += 1024) h[i] = 0;
  __syncthreads();
  int seg = blockIdx.x;
  int e0 = seg * segsz;
  int e1 = e0 + segsz; if (e1 > E) e1 = E;
  for (int e = e0 + threadIdx.x; e < e1; e += 1024)
    atomicAdd(&h[dsts[e] >> BSH], 1);
  __syncthreads();
  for (int i = threadIdx.x; i < NB; i += 1024) hist[seg * NB + i] = h[i];
}

// ---------------- phase 2a: per-bucket prefix over segments (1 wave / bucket) -------
__global__ __launch_bounds__(256) void segscanA(const int* __restrict__ hist,
                                                int* __restrict__ segoff,
                                                int* __restrict__ btot,
                                                int NB, int S){
  int wv = (blockIdx.x * 256 + threadIdx.x) >> 6;
  int lane = threadIdx.x & 63;
  if (wv >= NB) return;
  int b = wv;
  int run_base = 0;
  for (int chunk = 0; chunk < S; chunk += 64){
    int s = chunk + lane;
    int v = (s < S) ? hist[(size_t)s * NB + b] : 0;
    int x = v;
    #pragma unroll
    for (int o = 1; o < 64; o <<= 1){ int y = __shfl_up(x, o, 64); if (lane >= o) x += y; }
    if (s < S) segoff[(size_t)s * NB + b] = run_base + x - v;
    run_base += __shfl(x, 63, 64);
  }
  if (lane == 0) btot[b] = run_base;
}

// ---------------- phase 2b: exclusive scan of bucket totals (1 block) ----------------
__global__ __launch_bounds__(1024) void segscanB(const int* __restrict__ btot,
                                                 int* __restrict__ bbase, int NB){
  int t = threadIdx.x;
  int b0 = t * 2, b1 = t * 2 + 1;
  int v0 = (b0 < NB) ? btot[b0] : 0;
  int v1 = (b1 < NB) ? btot[b1] : 0;
  int pair = v0 + v1;
  int lane = t & 63, wid = t >> 6;
  int x = pair;
  for (int o = 1; o < 64; o <<= 1){ int y = __shfl_up(x, o, 64); if (lane >= o) x += y; }
  __shared__ int wsum[16]; __shared__ int woff[16];
  if (lane == 63) wsum[wid] = x;
  __syncthreads();
  if (t == 0){ int run = 0; for (int w = 0; w < 16; w++){ woff[w] = run; run += wsum[w]; } }
  __syncthreads();
  int excl = x - pair + woff[wid];
  if (b0 < NB) bbase[b0] = excl;
  if (b1 < NB) bbase[b1] = excl + v0;
}

// ---------------- phase 3: scatter 32-bit key (ld,eid), block-private regions ------
__global__ __launch_bounds__(1024) void scatter_kernel(const int* __restrict__ dsts,
                                                       const int* __restrict__ segoff,
                                                       const int* __restrict__ bbase,
                                                       unsigned* __restrict__ staging,
                                                       int E, int NB, int segsz){
  __shared__ int cur[HMAX];
  int seg = blockIdx.x;
  for (int i = threadIdx.x; i < NB; i += 1024) cur[i] = segoff[(size_t)seg * NB + i] + bbase[i];
  __syncthreads();
  int e0 = seg * segsz;
  int e1 = e0 + segsz; if (e1 > E) e1 = E;
  for (int e = e0 + threadIdx.x; e < e1; e += 1024){
    int d = dsts[e];
    int slot = atomicAdd(&cur[d >> BSH], 1);
    staging[slot] = ((unsigned)(d & (BNODES - 1)) << EID_BITS) | (unsigned)e;
  }
}

// ---------------- phase 4: per-bucket LDS bin + parallel rank -> CSR ----------------
__global__ __launch_bounds__(256) void bucket_sort_kernel(
    const int* __restrict__ bbase, const unsigned* __restrict__ staging,
    const int* __restrict__ srcs,
    int* __restrict__ csr, int* __restrict__ offs,
    float* __restrict__ dis, int N, int NB, int E){
  __shared__ unsigned ebuf[BCAP];
  __shared__ unsigned obuf[BCAP];
  __shared__ int cnt[BNODES];
  __shared__ int cur[BNODES];
  __shared__ int base0[BNODES];
  __shared__ int w0tot;
  int b = blockIdx.x, t = threadIdx.x;
  int n0 = b << BSH;
  int n1 = n0 + BNODES; if (n1 > N) n1 = N;
  int gbeg = bbase[b];
  int gend = (b + 1 < NB) ? bbase[b + 1] : E;
  int cnt_all = gend - gbeg;
  if (t < BNODES) cnt[t] = 0;
  __syncthreads();

  if (cnt_all <= BCAP){
    for (int i = t; i < cnt_all; i += 256){
      unsigned k = staging[gbeg + i];
      ebuf[i] = k;
      atomicAdd(&cnt[k >> EID_BITS], 1);
    }
    __syncthreads();
    int v = 0, x = 0;
    if (t < BNODES){
      v = cnt[t];
      int lane = t & 63, wid = t >> 6;
      x = v;
      for (int o = 1; o < 64; o <<= 1){ int y = __shfl_up(x, o, 64); if (lane >= o) x += y; }
      if (wid == 0 && lane == 63) w0tot = x;
    }
    __syncthreads();   // uniform: makes w0tot visible to wave 1
    if (t < BNODES){
      int wid = t >> 6;
      int ls = x - v + (wid ? w0tot : 0);
      cur[t] = ls;
      base0[t] = ls;
      int n = n0 + t;
      if (n < n1){
        float dd = (float)v + 1.0f;
        dis[n]  = __fdiv_rn(1.0f, __fsqrt_rn(dd));
        offs[n] = gbeg + ls;
      }
    }
    __syncthreads();
    for (int i = t; i < cnt_all; i += 256){
      unsigned k = ebuf[i];
      int pos = atomicAdd(&cur[k >> EID_BITS], 1);
      obuf[pos] = k;
    }
    __syncthreads();
    for (int i = t; i < cnt_all; i += 256){
      unsigned k = obuf[i];
      int nd = (int)(k >> EID_BITS);
      int base = base0[nd];
      int vn = cnt[nd];
      int r = 0;
      for (int j = 0; j < vn; j++) r += (obuf[base + j] < k) ? 1 : 0;
      csr[gbeg + base + r] = srcs[k & EID_MASK];
    }
  } else {
    // statistically unreachable fallback (correct, slow)
    if (t < BNODES){
      int n = n0 + t;
      int deg = 0;
      if (n < n1){
        for (int i = gbeg; i < gend; i++) if ((int)(staging[i] >> EID_BITS) == t) deg++;
        float dd = (float)deg + 1.0f;
        dis[n] = __fdiv_rn(1.0f, __fsqrt_rn(dd));
      }
      cnt[t] = (n < n1) ? deg : 0;
    }
    __syncthreads();
    if (t < BNODES){
      int n = n0 + t;
      if (n < n1){
        int deg = cnt[t];
        int ls = gbeg; for (int q = 0; q < t; q++) ls += cnt[q];
        offs[n] = ls;
        unsigned prev = 0;
        for (int o = 0; o < deg; o++){
          unsigned best = 0xFFFFFFFFu;
          for (int i = gbeg; i < gend; i++){
            unsigned k = staging[i];
            if ((int)(k >> EID_BITS) == t && (o == 0 || k > prev) && k < best) best = k;
          }
          csr[ls + o] = srcs[best & EID_MASK]; prev = best;
        }
      }
    }
  }
  if (b == 0 && t == 0) offs[N] = E;
}

// ---------------- per-node matmul h = x @ W ----------------
template<int K>
__global__ void node_matmul(const float* __restrict__ xin, const float* __restrict__ W,
                            float* __restrict__ H, int N){
  __shared__ float Ws[K * 32];
  for (int i = threadIdx.x; i < K * 32; i += blockDim.x) Ws[i] = W[i];
  __syncthreads();
  int tid = blockIdx.x * blockDim.x + threadIdx.x;
  int n = tid >> 5, c = tid & 31;
  if (n >= N) return;
  const float* xr = xin + (size_t)n * K;
  float acc = 0.f;
  #pragma unroll
  for (int k = 0; k < K; k++) acc = fmaf(xr[k], Ws[k * 32 + c], acc);
  H[(size_t)n * 32 + c] = acc;
}

// ---------------- GCN aggregation helpers ----------------
__device__ __forceinline__ float4 acc_edge(float4 a, float4 h, float w){
  a.x = __fadd_rn(a.x, __fmul_rn(h.x, w));
  a.y = __fadd_rn(a.y, __fmul_rn(h.y, w));
  a.z = __fadd_rn(a.z, __fmul_rn(h.z, w));
  a.w = __fadd_rn(a.w, __fmul_rn(h.w, w));
  return a;
}

// core agg body: returns v = relu(agg + selfterm + bias) for this lane's quad.
// r15 form (measured optimum): tiered 8/4/2/1-wide edge batching, 44 VGPR,
// ~46% occupancy. r16's deeper issue-all tail (64 VGPR) traded away occupancy
// and regressed -- the TLP x MLP balance point is here.
__device__ __forceinline__ float4 agg_body(const float* __restrict__ H,
                                           const int* __restrict__ offsets,
                                           const int* __restrict__ csr,
                                           const float* __restrict__ dis,
                                           const float* __restrict__ bias,
                                           int n, int qw){
  const float4* __restrict__ H4 = (const float4*)H;
  float dn = dis[n];
  int s = offsets[n], e = offsets[n + 1];
  float4 acc = make_float4(0.f, 0.f, 0.f, 0.f);
  int i = s;
  for (; i + 8 <= e; i += 8){
    int s0 = csr[i],   s1 = csr[i+1], s2 = csr[i+2], s3 = csr[i+3];
    int s4 = csr[i+4], s5 = csr[i+5], s6 = csr[i+6], s7 = csr[i+7];
    float4 h0 = H4[(size_t)s0 * 8 + qw];
    float4 h1 = H4[(size_t)s1 * 8 + qw];
    float4 h2 = H4[(size_t)s2 * 8 + qw];
    float4 h3 = H4[(size_t)s3 * 8 + qw];
    float4 h4 = H4[(size_t)s4 * 8 + qw];
    float4 h5 = H4[(size_t)s5 * 8 + qw];
    float4 h6 = H4[(size_t)s6 * 8 + qw];
    float4 h7 = H4[(size_t)s7 * 8 + qw];
    float w0 = __fmul_rn(dis[s0], dn), w1 = __fmul_rn(dis[s1], dn);
    float w2 = __fmul_rn(dis[s2], dn), w3 = __fmul_rn(dis[s3], dn);
    float w4 = __fmul_rn(dis[s4], dn), w5 = __fmul_rn(dis[s5], dn);
    float w6 = __fmul_rn(dis[s6], dn), w7 = __fmul_rn(dis[s7], dn);
    acc = acc_edge(acc, h0, w0);
    acc = acc_edge(acc, h1, w1);
    acc = acc_edge(acc, h2, w2);
    acc = acc_edge(acc, h3, w3);
    acc = acc_edge(acc, h4, w4);
    acc = acc_edge(acc, h5, w5);
    acc = acc_edge(acc, h6, w6);
    acc = acc_edge(acc, h7, w7);
  }
  if (i + 4 <= e){
    int s0 = csr[i], s1 = csr[i+1], s2 = csr[i+2], s3 = csr[i+3];
    float4 h0 = H4[(size_t)s0 * 8 + qw];
    float4 h1 = H4[(size_t)s1 * 8 + qw];
    float4 h2 = H4[(size_t)s2 * 8 + qw];
    float4 h3 = H4[(size_t)s3 * 8 + qw];
    float w0 = __fmul_rn(dis[s0], dn), w1 = __fmul_rn(dis[s1], dn);
    float w2 = __fmul_rn(dis[s2], dn), w3 = __fmul_rn(dis[s3], dn);
    acc = acc_edge(acc, h0, w0);
    acc = acc_edge(acc, h1, w1);
    acc = acc_edge(acc, h2, w2);
    acc = acc_edge(acc, h3, w3);
    i += 4;
  }
  if (i + 2 <= e){
    int s0 = csr[i], s1 = csr[i+1];
    float4 h0 = H4[(size_t)s0 * 8 + qw];
    float4 h1 = H4[(size_t)s1 * 8 + qw];
    float w0 = __fmul_rn(dis[s0], dn), w1 = __fmul_rn(dis[s1], dn);
    acc = acc_edge(acc, h0, w0);
    acc = acc_edge(acc, h1, w1);
    i += 2;
  }
  if (i < e){
    int sr = csr[i];
    float w = __fmul_rn(dis[sr], dn);
    acc = acc_edge(acc, H4[(size_t)sr * 8 + qw], w);
  }
  float4 hn = H4[(size_t)n * 8 + qw];
  float sw = __fmul_rn(dn, dn);
  float4 bb = ((const float4*)bias)[qw];
  float4 v;
  v.x = fmaxf(__fadd_rn(__fadd_rn(acc.x, __fmul_rn(hn.x, sw)), bb.x), 0.f);
  v.y = fmaxf(__fadd_rn(__fadd_rn(acc.y, __fmul_rn(hn.y, sw)), bb.y), 0.f);
  v.z = fmaxf(__fadd_rn(__fadd_rn(acc.z, __fmul_rn(hn.z, sw)), bb.z), 0.f);
  v.w = fmaxf(__fadd_rn(__fadd_rn(acc.w, __fmul_rn(hn.w, sw)), bb.w), 0.f);
  return v;
}

// final-layer agg: writes A (+ sort key)
__global__ __launch_bounds__(256) void agg_kernel(const float* __restrict__ H,
                           const int* __restrict__ offsets,
                           const int* __restrict__ csr, const float* __restrict__ dis,
                           const float* __restrict__ bias, float* __restrict__ A,
                           float* __restrict__ keyout, int N){
  int tid = blockIdx.x * 256 + threadIdx.x;
  int n = tid >> 3, qw = tid & 7;
  if (n >= N) return;
  float4 v = agg_body(H, offsets, csr, dis, bias, n, qw);
  ((float4*)A)[(size_t)n * 8 + qw] = v;
  if (keyout != nullptr && qw == 7) keyout[n] = v.w;
}

// fused agg + next-layer matmul (bit-identical to node_matmul<32>, k ascending)
__global__ __launch_bounds__(256) void agg_mm_kernel(const float* __restrict__ H,
                           const int* __restrict__ offsets,
                           const int* __restrict__ csr, const float* __restrict__ dis,
                           const float* __restrict__ bias,
                           const float* __restrict__ Wn,   // 32x32 row-major, L1-hot
                           float* __restrict__ H2, int N){
  int tid = blockIdx.x * 256 + threadIdx.x;
  int n = tid >> 3, qw = tid & 7;
  if (n >= N) return;   // whole 8-lane group exits together (node-aligned)
  float4 v = agg_body(H, offsets, csr, dis, bias, n, qw);

  const float4* __restrict__ Wn4 = (const float4*)Wn;  // Wn4[k*8 + col4]
  float4 o = make_float4(0.f, 0.f, 0.f, 0.f);
  #pragma unroll
  for (int p = 0; p < 8; p++){
    float4 hp;
    hp.x = __shfl(v.x, p, 8);
    hp.y = __shfl(v.y, p, 8);
    hp.z = __shfl(v.z, p, 8);
    hp.w = __shfl(v.w, p, 8);
    float4 wa = Wn4[(4 * p + 0) * 8 + qw];
    float4 wb = Wn4[(4 * p + 1) * 8 + qw];
    float4 wc = Wn4[(4 * p + 2) * 8 + qw];
    float4 wd = Wn4[(4 * p + 3) * 8 + qw];
    o.x = fmaf(hp.x, wa.x, o.x); o.y = fmaf(hp.x, wa.y, o.y);
    o.z = fmaf(hp.x, wa.z, o.z); o.w = fmaf(hp.x, wa.w, o.w);
    o.x = fmaf(hp.y, wb.x, o.x); o.y = fmaf(hp.y, wb.y, o.y);
    o.z = fmaf(hp.y, wb.z, o.z); o.w = fmaf(hp.y, wb.w, o.w);
    o.x = fmaf(hp.z, wc.x, o.x); o.y = fmaf(hp.z, wc.y, o.y);
    o.z = fmaf(hp.z, wc.z, o.z); o.w = fmaf(hp.z, wc.w, o.w);
    o.x = fmaf(hp.w, wd.x, o.x); o.y = fmaf(hp.w, wd.y, o.y);
    o.z = fmaf(hp.w, wd.z, o.z); o.w = fmaf(hp.w, wd.w, o.w);
  }
  ((float4*)H2)[(size_t)n * 8 + qw] = o;
}

// ---------------- graph boundaries (batch is sorted) ----------------
__global__ void gstarts_kernel(const int* __restrict__ batch, int* __restrict__ gstarts,
                               int N, int G){
  int g = blockIdx.x * blockDim.x + threadIdx.x;
  if (g > G) return;
  int lo = 0, hi = N;
  while (lo < hi){ int mid = (lo + hi) >> 1; if (batch[mid] < g) lo = mid + 1; else hi = mid; }
  gstarts[g] = lo;
}

// ------- fused head v5 (measured optimum of the graphs-per-wave family):
//   GPB=2 / 256-thread block, 128 threads = 2 waves per graph. ------
__global__ __launch_bounds__(256) void head_kernel(
    const float* __restrict__ A, const float* __restrict__ keys,
    const int* __restrict__ gstarts,
    const float* __restrict__ cw1, const float* __restrict__ cb1,
    const float* __restrict__ cw2, const float* __restrict__ cb2,
    const float* __restrict__ lw1, const float* __restrict__ lb1,
    const float* __restrict__ lw2, const float* __restrict__ lb2,
    float* __restrict__ out, int G){
  int t = threadIdx.x;
  int sub = t >> 7, lt = t & 127;    // waves 0-1 = graph 0, waves 2-3 = graph 1
  int g = blockIdx.x * GPB + sub;

  __shared__ float w1s[16 * 32 * 5];   // 2560, shared by both graphs
  __shared__ float w2s[32 * 16 * 5];   // 2560, shared by both graphs
  __shared__ float bufA[GPB][960];
  __shared__ float bufB[GPB][416];
  __shared__ int   sel[GPB][SORTK];

  for (int i = t; i < 2560; i += 256) w1s[i] = cw1[i];
  for (int i = t; i < 2560; i += 256) w2s[i] = cw2[i];
  for (int i = lt; i < 960; i += 128) bufA[sub][i] = 0.f;

  bool valid = (g < G);
  int s = 0, c = 0;
  if (valid){ s = gstarts[g]; c = gstarts[g + 1] - s; }
  bool fast = valid && (c <= KCAP);
  if (fast)
    for (int i = lt; i < c; i += 128) bufB[sub][i] = keys[s + i];   // coalesced
  __syncthreads();

  // stable top-30 rank: key desc, index asc (bit-identical selection)
  if (valid){
    if (fast){
      for (int i = lt; i < c; i += 128){
        float ki = bufB[sub][i];
        int rank = 0;
        #pragma unroll 8
        for (int j = 0; j < c; j++){
          float kj = bufB[sub][j];
          rank += (kj > ki || (kj == ki && j < i)) ? 1 : 0;
        }
        if (rank < SORTK) sel[sub][rank] = i;
      }
    } else {
      for (int i = lt; i < c; i += 128){
        float ki = keys[s + i];
        int rank = 0;
        for (int j = 0; j < c; j++){
          float kj = keys[s + j];
          if (kj > ki || (kj == ki && j < i)){
            if (++rank >= SORTK) break;
          }
        }
        if (rank < SORTK) sel[sub][rank] = i;
      }
    }
  }
  __syncthreads();

  // gather selected rows into conv layout sin_[ch*30+pos]
  if (valid){
    int kk = c < SORTK ? c : SORTK;
    for (int q = lt; q < kk * 32; q += 128){
      int pos = q >> 5, ch = q & 31;
      bufA[sub][ch * 30 + pos] = A[(size_t)(s + sel[sub][pos]) * 32 + ch];
    }
  }
  __syncthreads();

  // conv1: (32,30) -> (16,26)
  if (valid){
    for (int q = lt; q < 16 * 26; q += 128){
      int o = q / 26, tt = q - o * 26;
      float acc = cb1[o];
      const float* wo = &w1s[o * 160];
      #pragma unroll 4
      for (int i = 0; i < 32; i++){
        const float* si = &bufA[sub][i * 30 + tt];
        #pragma unroll
        for (int k = 0; k < 5; k++) acc = fmaf(si[k], wo[i * 5 + k], acc);
      }
      bufB[sub][q] = fmaxf(acc, 0.f);
    }
  }
  __syncthreads();

  // conv2: (16,26) -> (32,22)
  if (valid){
    for (int q = lt; q < 32 * 22; q += 128){
      int o = q / 22, tt = q - o * 22;
      float acc = cb2[o];
      const float* wo = &w2s[o * 80];
      #pragma unroll 4
      for (int i = 0; i < 16; i++){
        const float* si = &bufB[sub][i * 26 + tt];
        #pragma unroll
        for (int k = 0; k < 5; k++) acc = fmaf(si[k], wo[i * 5 + k], acc);
      }
      bufA[sub][q] = fmaxf(acc, 0.f);
    }
  }
  __syncthreads();

  // dense1: 704 -> 128; one thread per output, two accumulators preserving v4's
  // half-split FP order exactly: (lb1 + sum[0..351]) + (sum[352..703]), then relu.
  if (valid){
    int outi = lt;
    float accA = lb1[outi];
    float accB = 0.f;
    #pragma unroll 8
    for (int j = 0; j < 352; j++)
      accA = fmaf(bufA[sub][j], lw1[(size_t)j * 128 + outi], accA);
    #pragma unroll 8
    for (int j = 352; j < 704; j++)
      accB = fmaf(bufA[sub][j], lw1[(size_t)j * 128 + outi], accB);
    bufB[sub][outi] = fmaxf(accA + accB, 0.f);
  }
  __syncthreads();

  // dense2: 128 -> 1, one-wave shuffle reduce (lt<64 is a full wave in each sub)
  if (valid && lt < 64){
    float v = __fadd_rn(__fmul_rn(bufB[sub][lt], lw2[lt]),
                        __fmul_rn(bufB[sub][lt + 64], lw2[lt + 64]));
    #pragma unroll
    for (int o = 32; o > 0; o >>= 1) v += __shfl_xor(v, o, 64);
    if (lt == 0) out[g] = v + lb2[0];
  }
}

// ---------------- launch ----------------
extern "C" void kernel_launch(void* const* d_in, const int* in_sizes, int n_in,
                              void* d_out, int out_size, void* d_ws, size_t ws_size,
                              hipStream_t stream){
  const float* x     = (const float*)d_in[0];
  const int*   ei    = (const int*)  d_in[1];
  const int*   batch = (const int*)  d_in[2];
  const float* W1  = (const float*)d_in[4];
  const float* b1  = (const float*)d_in[5];
  const float* W2  = (const float*)d_in[6];
  const float* b2  = (const float*)d_in[7];
  const float* W3  = (const float*)d_in[8];
  const float* b3  = (const float*)d_in[9];
  const float* cw1 = (const float*)d_in[10];
  const float* cb1 = (const float*)d_in[11];
  const float* cw2 = (const float*)d_in[12];
  const float* cb2 = (const float*)d_in[13];
  const float* lw1 = (const float*)d_in[14];
  const float* lb1 = (const float*)d_in[15];
  const float* lw2 = (const float*)d_in[16];
  const float* lb2 = (const float*)d_in[17];

  int N = in_sizes[0] / 9;
  int E = in_sizes[1] / 2;
  int G = out_size;
  const int* srcs = ei;
  const int* dsts = ei + E;
  int NB = ceil_div_i(N, BNODES);
  int segsz = ceil_div_i(E, NSEG);

  char* base = (char*)d_ws;
  size_t off = 0;
  auto alloc = [&](size_t bytes) -> void* {
    off = (off + 255) & ~(size_t)255;
    void* r = base + off; off += bytes; return r;
  };
  float* dis    = (float*)alloc((size_t)N * 4);
  float* H      = (float*)alloc((size_t)N * 32 * 4);   // aliased as staging
  float* A      = (float*)alloc((size_t)N * 32 * 4);
  float* keyarr = (float*)alloc((size_t)N * 4);
  int*   offs   = (int*)alloc((size_t)(N + 1) * 4);
  int*   csr    = (int*)alloc((size_t)E * 4);
  int*   gst    = (int*)alloc((size_t)(G + 1) * 4);
  int*   hist   = (int*)alloc((size_t)NSEG * NB * 4);
  int*   segoff = (int*)alloc((size_t)NSEG * NB * 4);
  int*   btot   = (int*)alloc((size_t)NB * 4);
  int*   bbase  = (int*)alloc((size_t)(NB + 1) * 4);
  unsigned* staging = (unsigned*)H;
  (void)ws_size; (void)n_in;

  hist_kernel<<<NSEG, 1024, 0, stream>>>(dsts, hist, E, NB, segsz);
  segscanA<<<ceil_div_i(NB * 64, 256), 256, 0, stream>>>(hist, segoff, btot, NB, NSEG);
  segscanB<<<1, 1024, 0, stream>>>(btot, bbase, NB);
  scatter_kernel<<<NSEG, 1024, 0, stream>>>(dsts, segoff, bbase, staging, E, NB, segsz);
  bucket_sort_kernel<<<NB, 256, 0, stream>>>(bbase, staging, srcs, csr, offs, dis, N, NB, E);

  int ntm = ceil_div_i((long long)N * 32, 256);
  int nta = ceil_div_i((long long)N * 8, 256);
  // layer 1: H = x@W1 ; layer1 agg fused with matmul of W2 -> A holds next H
  node_matmul<9><<<ntm, 256, 0, stream>>>(x, W1, H, N);
  agg_mm_kernel<<<nta, 256, 0, stream>>>(H, offs, csr, dis, b1, W2, A, N);
  // layer 2: agg fused with matmul of W3 -> H holds next H
  agg_mm_kernel<<<nta, 256, 0, stream>>>(A, offs, csr, dis, b2, W3, H, N);
  // layer 3: plain agg -> A (+ sort keys) for the head
  agg_kernel<<<nta, 256, 0, stream>>>(H, offs, csr, dis, b3, A, keyarr, N);

  gstarts_kernel<<<ceil_div_i(G + 1, 256), 256, 0, stream>>>(batch, gst, N, G);
  head_kernel<<<ceil_div_i(G, GPB), 256, 0, stream>>>(A, keyarr, gst, cw1, cb1, cw2, cb2,
                                                      lw1, lb1, lw2, lb2, (float*)d_out, G);
}